// Round 1
// baseline (763.909 us; speedup 1.0000x reference)
//
#include <hip/hip_runtime.h>
#include <hip/hip_cooperative_groups.h>

namespace cg = cooperative_groups;

#define NN 50000
#define NE 800000
#define F_IN 128
#define HID 256
#define N_CLS 64
#define SCAN_BLOCKS ((NN + 255) / 256)   // 196
#define HB ((NE + 255) / 256)            // 3125 edge blocks
#define CF_BLOCKS 36                     // compose 515x256 tiles: 9 row x 4 col
#define CL_BLOCKS 9                      // compose 515x64 tiles
#define GA_BLOCKS ((NN + 127) / 128)     // 391 gemm row-blocks
#define CROWS 515                        // basis: X,AX,A2X,A3X (4*128) + 1,d,Ad

typedef _Float16 half8 __attribute__((ext_vector_type(8)));
typedef float f32x4 __attribute__((ext_vector_type(4)));

// ================= affine-map composition =================
__device__ __forceinline__ const float* virtC1_row(int r, const float* W0s,
                                                   const float* W0n, const float* b0) {
    if (r < 0) return nullptr;
    if (r < 128) return W0s + (size_t)r * 256;
    if (r < 256) return W0n + (size_t)(r - 128) * 256;
    if (r == 512) return b0;
    return nullptr;
}

__device__ __forceinline__ int shift_src(int r) {
    if (r >= 128 && r < 512) return r - 128;
    if (r == 513) return 512;
    if (r == 514) return 513;
    return -1;
}

__device__ __forceinline__ void compose_first_dev(
    int bx, const float* __restrict__ W0s, const float* __restrict__ W0n,
    const float* __restrict__ b0,
    const float* __restrict__ B1, const float* __restrict__ B2,
    const float* __restrict__ brow, float* __restrict__ C)
{
    __shared__ float As[64][17];
    __shared__ float Bs[16][64];
    const int tid = threadIdx.x;
    const int tx = tid & 15, ty = tid >> 4;
    const int row0 = (bx % 9) * 64;
    const int col0 = (bx / 9) * 64;
    const int lr = tid >> 2, lc = tid & 3;
    const int br = tid >> 4, bc = tid & 15;

    float acc[4][4] = {};

    for (int pass = 0; pass < 2; ++pass) {
        const float* B = pass ? B2 : B1;
        int grow = row0 + lr;
        int srcr = pass ? shift_src(grow) : (grow < CROWS ? grow : -1);
        const float* ap = virtC1_row(srcr, W0s, W0n, b0);

        for (int k0 = 0; k0 < 256; k0 += 16) {
            float4 av = make_float4(0.f, 0.f, 0.f, 0.f);
            if (ap) av = *(const float4*)(ap + k0 + lc * 4);
            As[lr][lc * 4 + 0] = av.x;
            As[lr][lc * 4 + 1] = av.y;
            As[lr][lc * 4 + 2] = av.z;
            As[lr][lc * 4 + 3] = av.w;
            *(float4*)&Bs[br][bc * 4] = *(const float4*)(B + (size_t)(k0 + br) * 256 + col0 + bc * 4);
            __syncthreads();
            #pragma unroll
            for (int k = 0; k < 16; ++k) {
                float a[4];
                #pragma unroll
                for (int i = 0; i < 4; ++i) a[i] = As[ty * 4 + i][k];
                float4 bv = *(const float4*)&Bs[k][tx * 4];
                const float b[4] = {bv.x, bv.y, bv.z, bv.w};
                #pragma unroll
                for (int i = 0; i < 4; ++i)
                    #pragma unroll
                    for (int j = 0; j < 4; ++j)
                        acc[i][j] += a[i] * b[j];
            }
            __syncthreads();
        }
    }

    #pragma unroll
    for (int i = 0; i < 4; ++i) {
        int r = row0 + ty * 4 + i;
        if (r < CROWS) {
            #pragma unroll
            for (int j = 0; j < 4; ++j) {
                float v = acc[i][j];
                if (r == 512) v += brow[col0 + tx * 4 + j];
                C[(size_t)r * 256 + col0 + tx * 4 + j] = v;
            }
        }
    }
}

__device__ __forceinline__ void compose_mid_dev(
    int bx, const float* __restrict__ A,
    const float* __restrict__ B1, const float* __restrict__ B2,
    const float* __restrict__ brow, float* __restrict__ C)
{
    __shared__ float As[64][17];
    __shared__ float Bs[16][64];
    const int tid = threadIdx.x;
    const int tx = tid & 15, ty = tid >> 4;
    const int row0 = (bx % 9) * 64;
    const int col0 = (bx / 9) * 64;
    const int lr = tid >> 2, lc = tid & 3;
    const int br = tid >> 4, bc = tid & 15;

    float acc[4][4] = {};

    for (int pass = 0; pass < 2; ++pass) {
        const float* B = pass ? B2 : B1;
        int grow = row0 + lr;
        int p = pass ? shift_src(grow) : (grow < CROWS ? grow : -1);

        for (int k0 = 0; k0 < 256; k0 += 16) {
            float4 av = make_float4(0.f, 0.f, 0.f, 0.f);
            if (p >= 0) av = *(const float4*)(A + (size_t)p * 256 + k0 + lc * 4);
            As[lr][lc * 4 + 0] = av.x;
            As[lr][lc * 4 + 1] = av.y;
            As[lr][lc * 4 + 2] = av.z;
            As[lr][lc * 4 + 3] = av.w;
            *(float4*)&Bs[br][bc * 4] = *(const float4*)(B + (size_t)(k0 + br) * 256 + col0 + bc * 4);
            __syncthreads();
            #pragma unroll
            for (int k = 0; k < 16; ++k) {
                float a[4];
                #pragma unroll
                for (int i = 0; i < 4; ++i) a[i] = As[ty * 4 + i][k];
                float4 bv = *(const float4*)&Bs[k][tx * 4];
                const float b[4] = {bv.x, bv.y, bv.z, bv.w};
                #pragma unroll
                for (int i = 0; i < 4; ++i)
                    #pragma unroll
                    for (int j = 0; j < 4; ++j)
                        acc[i][j] += a[i] * b[j];
            }
            __syncthreads();
        }
    }

    #pragma unroll
    for (int i = 0; i < 4; ++i) {
        int r = row0 + ty * 4 + i;
        if (r < CROWS) {
            #pragma unroll
            for (int j = 0; j < 4; ++j) {
                float v = acc[i][j];
                if (r == 512) v += brow[col0 + tx * 4 + j];
                C[(size_t)r * 256 + col0 + tx * 4 + j] = v;
            }
        }
    }
}

__device__ __forceinline__ void compose_last_dev(
    int bx, const float* __restrict__ A, const float* __restrict__ B1,
    const float* __restrict__ brow, float* __restrict__ Vf, _Float16* __restrict__ BT)
{
    __shared__ float As[64][17];
    __shared__ float Bs[16][64];
    const int tid = threadIdx.x;
    const int tx = tid & 15, ty = tid >> 4;
    const int row0 = bx * 64;
    const int lr = tid >> 2, lc = tid & 3;
    const int br = tid >> 4, bc = tid & 15;

    float acc[4][4] = {};

    for (int k0 = 0; k0 < 256; k0 += 16) {
        float4 av = make_float4(0.f, 0.f, 0.f, 0.f);
        int grow = row0 + lr;
        if (grow < CROWS) av = *(const float4*)(A + (size_t)grow * 256 + k0 + lc * 4);
        As[lr][lc * 4 + 0] = av.x;
        As[lr][lc * 4 + 1] = av.y;
        As[lr][lc * 4 + 2] = av.z;
        As[lr][lc * 4 + 3] = av.w;
        *(float4*)&Bs[br][bc * 4] = *(const float4*)(B1 + (size_t)(k0 + br) * 64 + bc * 4);
        __syncthreads();
        #pragma unroll
        for (int k = 0; k < 16; ++k) {
            float a[4];
            #pragma unroll
            for (int i = 0; i < 4; ++i) a[i] = As[ty * 4 + i][k];
            float4 bv = *(const float4*)&Bs[k][tx * 4];
            const float b[4] = {bv.x, bv.y, bv.z, bv.w};
            #pragma unroll
            for (int i = 0; i < 4; ++i)
                #pragma unroll
                for (int j = 0; j < 4; ++j)
                    acc[i][j] += a[i] * b[j];
        }
        __syncthreads();
    }

    #pragma unroll
    for (int i = 0; i < 4; ++i) {
        int r = row0 + ty * 4 + i;
        if (r < CROWS) {
            #pragma unroll
            for (int j = 0; j < 4; ++j) {
                int c = tx * 4 + j;
                float v = acc[i][j];
                if (r == 512) v += brow[c];
                Vf[(size_t)r * 64 + c] = v;
                if (r < 512)
                    BT[(size_t)((r >> 7) * 64 + c) * 128 + (r & 127)] = (_Float16)v;
            }
        }
    }
}

// ================= scan chain device pieces =================
__device__ __forceinline__ void scan_block_sums_dev(const int* __restrict__ cnt,
                                                    int* __restrict__ blockSums, int n, int bx) {
    __shared__ int s[256];
    int t = threadIdx.x;
    int i = bx * 256 + t;
    s[t] = (i < n) ? cnt[i] : 0;
    __syncthreads();
    for (int off = 128; off > 0; off >>= 1) {
        if (t < off) s[t] += s[t + off];
        __syncthreads();
    }
    if (t == 0) blockSums[bx] = s[0];
}

__device__ __forceinline__ void scan_top_dev(int* __restrict__ blockSums, int nb) {
    __shared__ int s[256];
    int t = threadIdx.x;
    s[t] = (t < nb) ? blockSums[t] : 0;
    __syncthreads();
    for (int off = 1; off < 256; off <<= 1) {
        int v = (t >= off) ? s[t - off] : 0;
        __syncthreads();
        s[t] += v;
        __syncthreads();
    }
    if (t < nb) blockSums[t] = (t > 0) ? s[t - 1] : 0;  // exclusive
}

__device__ __forceinline__ void scan_final_dev(const int* __restrict__ cnt,
                                               const int* __restrict__ blockBase,
                                               int* __restrict__ offs,
                                               float* __restrict__ dinv, int n, int bx) {
    __shared__ int s[256];
    int t = threadIdx.x;
    int i = bx * 256 + t;
    int v = (i < n) ? cnt[i] : 0;
    s[t] = v;
    __syncthreads();
    for (int off = 1; off < 256; off <<= 1) {
        int u = (t >= off) ? s[t - off] : 0;
        __syncthreads();
        s[t] += u;
        __syncthreads();
    }
    if (i < n) {
        offs[i] = blockBase[bx] + s[t] - v;
        dinv[i] = 1.0f / (float)max(v, 1);
    }
    if (i == n - 1) offs[n] = blockBase[bx] + s[t];
}

// ================= Y GEMM device piece =================
__device__ __forceinline__ void gemm_y_dev(
    int bx, int by,
    const float* __restrict__ X, const _Float16* __restrict__ BT,
    _Float16* __restrict__ Y, _Float16* __restrict__ Tc, int N)
{
    constexpr int LP = 40;
    __shared__ _Float16 As[128 * LP];
    __shared__ _Float16 Bs[128 * LP];

    const int tid = threadIdx.x;
    const int wave = tid >> 6;
    const int lane = tid & 63;
    const int l15 = lane & 15;
    const int quad = lane >> 4;
    const int wrow = wave >> 1;
    const int wcol = wave & 1;
    const int m_base = wrow * 64;
    const int n_base = wcol * 64;

    const int row0 = bx * 128;
    const int col0 = by * 128;

    f32x4 acc[4][4] = {};

    for (int k0 = 0; k0 < 128; k0 += 32) {
        #pragma unroll
        for (int r = 0; r < 2; ++r) {
            int idx = r * 256 + tid;
            int row = idx >> 2, ch = idx & 3;
            int gr = row0 + row; if (gr > N - 1) gr = N - 1;
            const float* ap = X + (size_t)gr * 128 + k0 + ch * 8;
            float4 f0 = *(const float4*)ap;
            float4 f1 = *(const float4*)(ap + 4);
            half8 v = { (_Float16)f0.x, (_Float16)f0.y, (_Float16)f0.z, (_Float16)f0.w,
                        (_Float16)f1.x, (_Float16)f1.y, (_Float16)f1.z, (_Float16)f1.w };
            *(half8*)&As[row * LP + ch * 8] = v;
        }
        #pragma unroll
        for (int r = 0; r < 2; ++r) {
            int idx = r * 256 + tid;
            int row = idx >> 2, ch = idx & 3;
            *(half8*)&Bs[row * LP + ch * 8] =
                *(const half8*)(BT + (size_t)(col0 + row) * 128 + k0 + ch * 8);
        }
        __syncthreads();
        half8 af[4], bf[4];
        #pragma unroll
        for (int i = 0; i < 4; ++i)
            af[i] = *(const half8*)&As[(m_base + i * 16 + l15) * LP + quad * 8];
        #pragma unroll
        for (int j = 0; j < 4; ++j)
            bf[j] = *(const half8*)&Bs[(n_base + j * 16 + l15) * LP + quad * 8];
        #pragma unroll
        for (int i = 0; i < 4; ++i)
            #pragma unroll
            for (int j = 0; j < 4; ++j)
                acc[i][j] = __builtin_amdgcn_mfma_f32_16x16x32_f16(af[i], bf[j], acc[i][j], 0, 0, 0);
        __syncthreads();
    }

    #pragma unroll
    for (int i = 0; i < 4; ++i) {
        #pragma unroll
        for (int j = 0; j < 4; ++j) {
            int col = col0 + n_base + j * 16 + l15;
            #pragma unroll
            for (int r = 0; r < 4; ++r) {
                int row = row0 + m_base + i * 16 + quad * 4 + r;
                if (row < N) {
                    _Float16 v = (_Float16)acc[i][j][r];
                    Y[(size_t)row * 256 + col] = v;
                    if (col >= 192) Tc[(size_t)row * 64 + (col - 192)] = v;
                }
            }
        }
    }
}

// ================= packed pipeline kernels =================
// D2: composeF (weights only)  ||  hist (edst only; cnt zeroed by memset)
__global__ __launch_bounds__(256) void k_composeF_hist(
    const int* __restrict__ edst, int* __restrict__ cnt, unsigned short* __restrict__ rank,
    const float* __restrict__ W0s, const float* __restrict__ W0n, const float* __restrict__ b0,
    const float* __restrict__ W1s, const float* __restrict__ W1n, const float* __restrict__ b1,
    float* __restrict__ C2)
{
    if (blockIdx.x < CF_BLOCKS) {
        compose_first_dev(blockIdx.x, W0s, W0n, b0, W1s, W1n, b1, C2);
    } else {
        int e = (blockIdx.x - CF_BLOCKS) * 256 + threadIdx.x;
        if (e < NE) rank[e] = (unsigned short)atomicAdd(&cnt[edst[e]], 1);
    }
}

// D3: composeM (needs C2)  ||  scanA (needs cnt complete)
__global__ __launch_bounds__(256) void k_composeM_scanA(
    const int* __restrict__ cnt, int* __restrict__ blockSums,
    const float* __restrict__ C2,
    const float* __restrict__ W2s, const float* __restrict__ W2n, const float* __restrict__ b2,
    float* __restrict__ C3)
{
    if (blockIdx.x < CF_BLOCKS) compose_mid_dev(blockIdx.x, C2, W2s, W2n, b2, C3);
    else scan_block_sums_dev(cnt, blockSums, NN, blockIdx.x - CF_BLOCKS);
}

// D4: scanT (needs blockSums) || composeL (needs C3)
__global__ __launch_bounds__(256) void k_scanT_composeL(
    int* __restrict__ blockSums,
    const float* __restrict__ C3, const float* __restrict__ Wfc, const float* __restrict__ bfc,
    float* __restrict__ Vf, _Float16* __restrict__ BT)
{
    if (blockIdx.x == 0) scan_top_dev(blockSums, SCAN_BLOCKS);
    else compose_last_dev(blockIdx.x - 1, C3, Wfc, bfc, Vf, BT);
}

// D5: gemm cols 0..127 (needs BT) || scanF (needs scanT)
__global__ __launch_bounds__(256) void k_gemmA_scanF(
    const int* __restrict__ cnt, const int* __restrict__ blockBase,
    int* __restrict__ offs, float* __restrict__ dinv,
    const float* __restrict__ X, const _Float16* __restrict__ BT,
    _Float16* __restrict__ Y, _Float16* __restrict__ Tc)
{
    if (blockIdx.x < GA_BLOCKS) gemm_y_dev(blockIdx.x, 0, X, BT, Y, Tc, NN);
    else scan_final_dev(cnt, blockBase, offs, dinv, NN, blockIdx.x - GA_BLOCKS);
}

// D6: gemm cols 128..255 + Tc copy || place (needs offs)
__global__ __launch_bounds__(256) void k_gemmB_place(
    const int* __restrict__ esrc, const int* __restrict__ edst,
    const unsigned short* __restrict__ rank, const int* __restrict__ offs,
    unsigned short* __restrict__ csr,
    const float* __restrict__ X, const _Float16* __restrict__ BT,
    _Float16* __restrict__ Y, _Float16* __restrict__ Tc)
{
    if (blockIdx.x < GA_BLOCKS) {
        gemm_y_dev(blockIdx.x, 1, X, BT, Y, Tc, NN);
    } else {
        int e = (blockIdx.x - GA_BLOCKS) * 256 + threadIdx.x;
        if (e < NE) csr[offs[edst[e]] + rank[e]] = (unsigned short)esrc[e];
    }
}

// ================= output-side gather =================
template <bool OUT_F32>
__device__ __forceinline__ void gather_node_dev(
    int node, int lane,
    const _Float16* __restrict__ Tin,
    const unsigned short* __restrict__ csr, const int* __restrict__ offs,
    const float* __restrict__ dinv,
    const _Float16* __restrict__ Yadd,
    const float* __restrict__ cvec,
    void* __restrict__ Tout)
{
    int beg = offs[node], end = offs[node + 1];
    float acc[8] = {};
    int e = beg;
    for (; e + 3 < end; e += 4) {
        int s0 = csr[e], s1 = csr[e + 1], s2 = csr[e + 2], s3 = csr[e + 3];
        half8 v0 = *(const half8*)(Tin + (size_t)s0 * 64 + lane * 8);
        half8 v1 = *(const half8*)(Tin + (size_t)s1 * 64 + lane * 8);
        half8 v2 = *(const half8*)(Tin + (size_t)s2 * 64 + lane * 8);
        half8 v3 = *(const half8*)(Tin + (size_t)s3 * 64 + lane * 8);
        #pragma unroll
        for (int j = 0; j < 8; ++j)
            acc[j] += ((float)v0[j] + (float)v1[j]) + ((float)v2[j] + (float)v3[j]);
    }
    for (; e < end; ++e) {
        half8 v = *(const half8*)(Tin + (size_t)csr[e] * 64 + lane * 8);
        #pragma unroll
        for (int j = 0; j < 8; ++j) acc[j] += (float)v[j];
    }
    float sc = dinv[node];
    half8 y = *(const half8*)(Yadd + (size_t)node * 256 + lane * 8);
    if (OUT_F32) {
        float* o = (float*)Tout + (size_t)node * 64 + lane * 8;
        float4 o0, o1;
        o0.x = acc[0] * sc + (float)y[0] + cvec[lane * 8 + 0];
        o0.y = acc[1] * sc + (float)y[1] + cvec[lane * 8 + 1];
        o0.z = acc[2] * sc + (float)y[2] + cvec[lane * 8 + 2];
        o0.w = acc[3] * sc + (float)y[3] + cvec[lane * 8 + 3];
        o1.x = acc[4] * sc + (float)y[4] + cvec[lane * 8 + 4];
        o1.y = acc[5] * sc + (float)y[5] + cvec[lane * 8 + 5];
        o1.z = acc[6] * sc + (float)y[6] + cvec[lane * 8 + 6];
        o1.w = acc[7] * sc + (float)y[7] + cvec[lane * 8 + 7];
        *(float4*)o = o0;
        *(float4*)(o + 4) = o1;
    } else {
        half8 o;
        #pragma unroll
        for (int j = 0; j < 8; ++j)
            o[j] = (_Float16)(acc[j] * sc + (float)y[j] + cvec[lane * 8 + j]);
        *(half8*)((_Float16*)Tout + (size_t)node * 64 + lane * 8) = o;
    }
}

// D7: all three gather passes in one cooperative kernel (grid.sync between passes)
__global__ __launch_bounds__(256, 6) void coop_gather(
    const _Float16* __restrict__ Tc, _Float16* __restrict__ Ta, _Float16* __restrict__ Tb,
    const unsigned short* __restrict__ csr, const int* __restrict__ offs,
    const float* __restrict__ dinv, const _Float16* __restrict__ Y,
    const float* __restrict__ Vf, float* __restrict__ out)
{
    cg::grid_group grid = cg::this_grid();
    const int g = threadIdx.x >> 3;
    const int lane = threadIdx.x & 7;

    for (int base = blockIdx.x * 32; base < NN; base += gridDim.x * 32) {
        int node = base + g;
        if (node < NN)
            gather_node_dev<false>(node, lane, Tc, csr, offs, dinv,
                                   Y + 128, Vf + (size_t)514 * 64, (void*)Ta);
    }
    __threadfence();
    grid.sync();
    for (int base = blockIdx.x * 32; base < NN; base += gridDim.x * 32) {
        int node = base + g;
        if (node < NN)
            gather_node_dev<false>(node, lane, Ta, csr, offs, dinv,
                                   Y + 64, Vf + (size_t)513 * 64, (void*)Tb);
    }
    __threadfence();
    grid.sync();
    for (int base = blockIdx.x * 32; base < NN; base += gridDim.x * 32) {
        int node = base + g;
        if (node < NN)
            gather_node_dev<true>(node, lane, Tb, csr, offs, dinv,
                                  Y, Vf + (size_t)512 * 64, (void*)out);
    }
}

// fallback (non-cooperative) gather, one pass per dispatch
template <bool OUT_F32>
__global__ __launch_bounds__(256) void gather64(
    const _Float16* __restrict__ Tin,
    const unsigned short* __restrict__ csr, const int* __restrict__ offs,
    const float* __restrict__ dinv,
    const _Float16* __restrict__ Yadd,
    const float* __restrict__ cvec,
    void* __restrict__ Tout, int N)
{
    int node = blockIdx.x * 32 + (threadIdx.x >> 3);
    int lane = threadIdx.x & 7;
    if (node >= N) return;
    gather_node_dev<OUT_F32>(node, lane, Tin, csr, offs, dinv, Yadd, cvec, Tout);
}

extern "C" void kernel_launch(void* const* d_in, const int* in_sizes, int n_in,
                              void* d_out, int out_size, void* d_ws, size_t ws_size,
                              hipStream_t stream) {
    const float* x    = (const float*)d_in[0];
    const int*   esrc = (const int*)d_in[1];
    const int*   edst = (const int*)d_in[2];
    const float* W0s  = (const float*)d_in[3];
    const float* W0n  = (const float*)d_in[4];
    const float* b0   = (const float*)d_in[5];
    const float* W1s  = (const float*)d_in[6];
    const float* W1n  = (const float*)d_in[7];
    const float* b1   = (const float*)d_in[8];
    const float* W2s  = (const float*)d_in[9];
    const float* W2n  = (const float*)d_in[10];
    const float* b2   = (const float*)d_in[11];
    const float* Wfc  = (const float*)d_in[12];
    const float* bfc  = (const float*)d_in[13];
    float* out = (float*)d_out;

    // ---- workspace layout ----
    _Float16* Y   = (_Float16*)d_ws;                  // N x 256  [Y0|Y1|Y2|Y3]
    _Float16* Ta  = Y + (size_t)NN * 256;             // N x 64
    _Float16* Tb  = Ta + (size_t)NN * 64;             // N x 64
    _Float16* Tc  = Tb + (size_t)NN * 64;             // N x 64 (dense Y3 copy)
    _Float16* BT  = Tc + (size_t)NN * 64;             // 256 x 128
    float* C2     = (float*)(BT + 256 * 128);         // 515 x 256
    float* C3     = C2 + CROWS * 256;                 // 515 x 256
    float* Vf     = C3 + CROWS * 256;                 // 515 x 64
    float* dinv   = Vf + CROWS * 64;                  // N
    int* cnt      = (int*)(dinv + NN);                // N   (memset target)
    int* offs     = cnt + NN;                         // N+1
    int* blockSums = offs + NN + 1;                   // SCAN_BLOCKS
    unsigned short* rank = (unsigned short*)(blockSums + SCAN_BLOCKS);  // E
    unsigned short* csr  = rank + NE;                 // E

    // D1: zero the histogram counters
    hipMemsetAsync(cnt, 0, (size_t)NN * sizeof(int), stream);

    // D2: weight-compose layer0->1  ||  degree histogram (+rank)
    k_composeF_hist<<<CF_BLOCKS + HB, 256, 0, stream>>>(
        edst, cnt, rank, W0s, W0n, b0, W1s, W1n, b1, C2);

    // D3: weight-compose layer2  ||  per-block degree sums
    k_composeM_scanA<<<CF_BLOCKS + SCAN_BLOCKS, 256, 0, stream>>>(
        cnt, blockSums, C2, W2s, W2n, b2, C3);

    // D4: top-level scan || final compose (Vf + BT)
    k_scanT_composeL<<<1 + CL_BLOCKS, 256, 0, stream>>>(
        blockSums, C3, Wfc, bfc, Vf, BT);

    // D5: gemm Y cols 0..127 || final scan (offs, dinv)
    k_gemmA_scanF<<<GA_BLOCKS + SCAN_BLOCKS, 256, 0, stream>>>(
        cnt, blockSums, offs, dinv, x, BT, Y, Tc);

    // D6: gemm Y cols 128..255 (+Tc) || CSR placement
    k_gemmB_place<<<GA_BLOCKS + HB, 256, 0, stream>>>(
        esrc, edst, rank, offs, csr, x, BT, Y, Tc);

    // D7: three Horner gather passes, cooperative
    static int coopb = 0;
    if (coopb == 0) {
        int maxb = 0;
        if (hipOccupancyMaxActiveBlocksPerMultiprocessor(&maxb, coop_gather, 256, 0) != hipSuccess
            || maxb < 1) maxb = 1;
        if (maxb > 8) maxb = 8;
        coopb = 256 * maxb;   // 256 CUs on MI355X, maxb blocks/CU co-resident
    }
    {
        const _Float16* a0 = Tc; _Float16* a1 = Ta; _Float16* a2 = Tb;
        const unsigned short* a3 = csr; const int* a4 = offs; const float* a5 = dinv;
        const _Float16* a6 = Y; const float* a7 = Vf; float* a8 = out;
        void* kargs[] = {&a0, &a1, &a2, &a3, &a4, &a5, &a6, &a7, &a8};
        hipError_t ce = hipLaunchCooperativeKernel(
            coop_gather, dim3(coopb), dim3(256), kargs, 0, stream);
        if (ce != hipSuccess) {
            // fallback: three plain dispatches (kernel boundaries provide the sync)
            const int ggrid = (NN + 31) / 32;
            gather64<false><<<ggrid, 256, 0, stream>>>(
                Tc, csr, offs, dinv, Y + 128, Vf + (size_t)514 * 64, (void*)Ta, NN);
            gather64<false><<<ggrid, 256, 0, stream>>>(
                Ta, csr, offs, dinv, Y + 64, Vf + (size_t)513 * 64, (void*)Tb, NN);
            gather64<true><<<ggrid, 256, 0, stream>>>(
                Tb, csr, offs, dinv, Y, Vf + (size_t)512 * 64, (void*)out, NN);
        }
    }
}

// Round 2
// 288.212 us; speedup vs baseline: 2.6505x; 2.6505x over previous
//
#include <hip/hip_runtime.h>

#define NN 50000
#define NE 800000
#define F_IN 128
#define HID 256
#define N_CLS 64
#define SCAN_BLOCKS ((NN + 255) / 256)   // 196
#define HB ((NE + 255) / 256)            // 3125 edge blocks
#define CF_BLOCKS 36                     // compose 515x256 tiles: 9 row x 4 col
#define CL_BLOCKS 9                      // compose 515x64 tiles
#define GA_BLOCKS ((NN + 127) / 128)     // 391 gemm row-blocks
#define CROWS 515                        // basis: X,AX,A2X,A3X (4*128) + 1,d,Ad

typedef _Float16 half8 __attribute__((ext_vector_type(8)));
typedef float f32x4 __attribute__((ext_vector_type(4)));

// ================= affine-map composition =================
__device__ __forceinline__ const float* virtC1_row(int r, const float* W0s,
                                                   const float* W0n, const float* b0) {
    if (r < 0) return nullptr;
    if (r < 128) return W0s + (size_t)r * 256;
    if (r < 256) return W0n + (size_t)(r - 128) * 256;
    if (r == 512) return b0;
    return nullptr;
}

__device__ __forceinline__ int shift_src(int r) {
    if (r >= 128 && r < 512) return r - 128;
    if (r == 513) return 512;
    if (r == 514) return 513;
    return -1;
}

__device__ __forceinline__ void compose_first_dev(
    int bx, const float* __restrict__ W0s, const float* __restrict__ W0n,
    const float* __restrict__ b0,
    const float* __restrict__ B1, const float* __restrict__ B2,
    const float* __restrict__ brow, float* __restrict__ C)
{
    __shared__ float As[64][17];
    __shared__ float Bs[16][64];
    const int tid = threadIdx.x;
    const int tx = tid & 15, ty = tid >> 4;
    const int row0 = (bx % 9) * 64;
    const int col0 = (bx / 9) * 64;
    const int lr = tid >> 2, lc = tid & 3;
    const int br = tid >> 4, bc = tid & 15;

    float acc[4][4] = {};

    for (int pass = 0; pass < 2; ++pass) {
        const float* B = pass ? B2 : B1;
        int grow = row0 + lr;
        int srcr = pass ? shift_src(grow) : (grow < CROWS ? grow : -1);
        const float* ap = virtC1_row(srcr, W0s, W0n, b0);

        for (int k0 = 0; k0 < 256; k0 += 16) {
            float4 av = make_float4(0.f, 0.f, 0.f, 0.f);
            if (ap) av = *(const float4*)(ap + k0 + lc * 4);
            As[lr][lc * 4 + 0] = av.x;
            As[lr][lc * 4 + 1] = av.y;
            As[lr][lc * 4 + 2] = av.z;
            As[lr][lc * 4 + 3] = av.w;
            *(float4*)&Bs[br][bc * 4] = *(const float4*)(B + (size_t)(k0 + br) * 256 + col0 + bc * 4);
            __syncthreads();
            #pragma unroll
            for (int k = 0; k < 16; ++k) {
                float a[4];
                #pragma unroll
                for (int i = 0; i < 4; ++i) a[i] = As[ty * 4 + i][k];
                float4 bv = *(const float4*)&Bs[k][tx * 4];
                const float b[4] = {bv.x, bv.y, bv.z, bv.w};
                #pragma unroll
                for (int i = 0; i < 4; ++i)
                    #pragma unroll
                    for (int j = 0; j < 4; ++j)
                        acc[i][j] += a[i] * b[j];
            }
            __syncthreads();
        }
    }

    #pragma unroll
    for (int i = 0; i < 4; ++i) {
        int r = row0 + ty * 4 + i;
        if (r < CROWS) {
            #pragma unroll
            for (int j = 0; j < 4; ++j) {
                float v = acc[i][j];
                if (r == 512) v += brow[col0 + tx * 4 + j];
                C[(size_t)r * 256 + col0 + tx * 4 + j] = v;
            }
        }
    }
}

__device__ __forceinline__ void compose_mid_dev(
    int bx, const float* __restrict__ A,
    const float* __restrict__ B1, const float* __restrict__ B2,
    const float* __restrict__ brow, float* __restrict__ C)
{
    __shared__ float As[64][17];
    __shared__ float Bs[16][64];
    const int tid = threadIdx.x;
    const int tx = tid & 15, ty = tid >> 4;
    const int row0 = (bx % 9) * 64;
    const int col0 = (bx / 9) * 64;
    const int lr = tid >> 2, lc = tid & 3;
    const int br = tid >> 4, bc = tid & 15;

    float acc[4][4] = {};

    for (int pass = 0; pass < 2; ++pass) {
        const float* B = pass ? B2 : B1;
        int grow = row0 + lr;
        int p = pass ? shift_src(grow) : (grow < CROWS ? grow : -1);

        for (int k0 = 0; k0 < 256; k0 += 16) {
            float4 av = make_float4(0.f, 0.f, 0.f, 0.f);
            if (p >= 0) av = *(const float4*)(A + (size_t)p * 256 + k0 + lc * 4);
            As[lr][lc * 4 + 0] = av.x;
            As[lr][lc * 4 + 1] = av.y;
            As[lr][lc * 4 + 2] = av.z;
            As[lr][lc * 4 + 3] = av.w;
            *(float4*)&Bs[br][bc * 4] = *(const float4*)(B + (size_t)(k0 + br) * 256 + col0 + bc * 4);
            __syncthreads();
            #pragma unroll
            for (int k = 0; k < 16; ++k) {
                float a[4];
                #pragma unroll
                for (int i = 0; i < 4; ++i) a[i] = As[ty * 4 + i][k];
                float4 bv = *(const float4*)&Bs[k][tx * 4];
                const float b[4] = {bv.x, bv.y, bv.z, bv.w};
                #pragma unroll
                for (int i = 0; i < 4; ++i)
                    #pragma unroll
                    for (int j = 0; j < 4; ++j)
                        acc[i][j] += a[i] * b[j];
            }
            __syncthreads();
        }
    }

    #pragma unroll
    for (int i = 0; i < 4; ++i) {
        int r = row0 + ty * 4 + i;
        if (r < CROWS) {
            #pragma unroll
            for (int j = 0; j < 4; ++j) {
                float v = acc[i][j];
                if (r == 512) v += brow[col0 + tx * 4 + j];
                C[(size_t)r * 256 + col0 + tx * 4 + j] = v;
            }
        }
    }
}

__device__ __forceinline__ void compose_last_dev(
    int bx, const float* __restrict__ A, const float* __restrict__ B1,
    const float* __restrict__ brow, float* __restrict__ Vf, _Float16* __restrict__ BT)
{
    __shared__ float As[64][17];
    __shared__ float Bs[16][64];
    const int tid = threadIdx.x;
    const int tx = tid & 15, ty = tid >> 4;
    const int row0 = bx * 64;
    const int lr = tid >> 2, lc = tid & 3;
    const int br = tid >> 4, bc = tid & 15;

    float acc[4][4] = {};

    for (int k0 = 0; k0 < 256; k0 += 16) {
        float4 av = make_float4(0.f, 0.f, 0.f, 0.f);
        int grow = row0 + lr;
        if (grow < CROWS) av = *(const float4*)(A + (size_t)grow * 256 + k0 + lc * 4);
        As[lr][lc * 4 + 0] = av.x;
        As[lr][lc * 4 + 1] = av.y;
        As[lr][lc * 4 + 2] = av.z;
        As[lr][lc * 4 + 3] = av.w;
        *(float4*)&Bs[br][bc * 4] = *(const float4*)(B1 + (size_t)(k0 + br) * 64 + bc * 4);
        __syncthreads();
        #pragma unroll
        for (int k = 0; k < 16; ++k) {
            float a[4];
            #pragma unroll
            for (int i = 0; i < 4; ++i) a[i] = As[ty * 4 + i][k];
            float4 bv = *(const float4*)&Bs[k][tx * 4];
            const float b[4] = {bv.x, bv.y, bv.z, bv.w};
            #pragma unroll
            for (int i = 0; i < 4; ++i)
                #pragma unroll
                for (int j = 0; j < 4; ++j)
                    acc[i][j] += a[i] * b[j];
        }
        __syncthreads();
    }

    #pragma unroll
    for (int i = 0; i < 4; ++i) {
        int r = row0 + ty * 4 + i;
        if (r < CROWS) {
            #pragma unroll
            for (int j = 0; j < 4; ++j) {
                int c = tx * 4 + j;
                float v = acc[i][j];
                if (r == 512) v += brow[c];
                Vf[(size_t)r * 64 + c] = v;
                if (r < 512)
                    BT[(size_t)((r >> 7) * 64 + c) * 128 + (r & 127)] = (_Float16)v;
            }
        }
    }
}

// ================= scan chain device pieces =================
__device__ __forceinline__ void scan_block_sums_dev(const int* __restrict__ cnt,
                                                    int* __restrict__ blockSums, int n, int bx) {
    __shared__ int s[256];
    int t = threadIdx.x;
    int i = bx * 256 + t;
    s[t] = (i < n) ? cnt[i] : 0;
    __syncthreads();
    for (int off = 128; off > 0; off >>= 1) {
        if (t < off) s[t] += s[t + off];
        __syncthreads();
    }
    if (t == 0) blockSums[bx] = s[0];
}

__device__ __forceinline__ void scan_top_dev(int* __restrict__ blockSums, int nb) {
    __shared__ int s[256];
    int t = threadIdx.x;
    s[t] = (t < nb) ? blockSums[t] : 0;
    __syncthreads();
    for (int off = 1; off < 256; off <<= 1) {
        int v = (t >= off) ? s[t - off] : 0;
        __syncthreads();
        s[t] += v;
        __syncthreads();
    }
    if (t < nb) blockSums[t] = (t > 0) ? s[t - 1] : 0;  // exclusive
}

__device__ __forceinline__ void scan_final_dev(const int* __restrict__ cnt,
                                               const int* __restrict__ blockBase,
                                               int* __restrict__ offs,
                                               float* __restrict__ dinv, int n, int bx) {
    __shared__ int s[256];
    int t = threadIdx.x;
    int i = bx * 256 + t;
    int v = (i < n) ? cnt[i] : 0;
    s[t] = v;
    __syncthreads();
    for (int off = 1; off < 256; off <<= 1) {
        int u = (t >= off) ? s[t - off] : 0;
        __syncthreads();
        s[t] += u;
        __syncthreads();
    }
    if (i < n) {
        offs[i] = blockBase[bx] + s[t] - v;
        dinv[i] = 1.0f / (float)max(v, 1);
    }
    if (i == n - 1) offs[n] = blockBase[bx] + s[t];
}

// ================= Y GEMM device piece =================
__device__ __forceinline__ void gemm_y_dev(
    int bx, int by,
    const float* __restrict__ X, const _Float16* __restrict__ BT,
    _Float16* __restrict__ Y, _Float16* __restrict__ Tc, int N)
{
    constexpr int LP = 40;
    __shared__ _Float16 As[128 * LP];
    __shared__ _Float16 Bs[128 * LP];

    const int tid = threadIdx.x;
    const int wave = tid >> 6;
    const int lane = tid & 63;
    const int l15 = lane & 15;
    const int quad = lane >> 4;
    const int wrow = wave >> 1;
    const int wcol = wave & 1;
    const int m_base = wrow * 64;
    const int n_base = wcol * 64;

    const int row0 = bx * 128;
    const int col0 = by * 128;

    f32x4 acc[4][4] = {};

    for (int k0 = 0; k0 < 128; k0 += 32) {
        #pragma unroll
        for (int r = 0; r < 2; ++r) {
            int idx = r * 256 + tid;
            int row = idx >> 2, ch = idx & 3;
            int gr = row0 + row; if (gr > N - 1) gr = N - 1;
            const float* ap = X + (size_t)gr * 128 + k0 + ch * 8;
            float4 f0 = *(const float4*)ap;
            float4 f1 = *(const float4*)(ap + 4);
            half8 v = { (_Float16)f0.x, (_Float16)f0.y, (_Float16)f0.z, (_Float16)f0.w,
                        (_Float16)f1.x, (_Float16)f1.y, (_Float16)f1.z, (_Float16)f1.w };
            *(half8*)&As[row * LP + ch * 8] = v;
        }
        #pragma unroll
        for (int r = 0; r < 2; ++r) {
            int idx = r * 256 + tid;
            int row = idx >> 2, ch = idx & 3;
            *(half8*)&Bs[row * LP + ch * 8] =
                *(const half8*)(BT + (size_t)(col0 + row) * 128 + k0 + ch * 8);
        }
        __syncthreads();
        half8 af[4], bf[4];
        #pragma unroll
        for (int i = 0; i < 4; ++i)
            af[i] = *(const half8*)&As[(m_base + i * 16 + l15) * LP + quad * 8];
        #pragma unroll
        for (int j = 0; j < 4; ++j)
            bf[j] = *(const half8*)&Bs[(n_base + j * 16 + l15) * LP + quad * 8];
        #pragma unroll
        for (int i = 0; i < 4; ++i)
            #pragma unroll
            for (int j = 0; j < 4; ++j)
                acc[i][j] = __builtin_amdgcn_mfma_f32_16x16x32_f16(af[i], bf[j], acc[i][j], 0, 0, 0);
        __syncthreads();
    }

    #pragma unroll
    for (int i = 0; i < 4; ++i) {
        #pragma unroll
        for (int j = 0; j < 4; ++j) {
            int col = col0 + n_base + j * 16 + l15;
            #pragma unroll
            for (int r = 0; r < 4; ++r) {
                int row = row0 + m_base + i * 16 + quad * 4 + r;
                if (row < N) {
                    _Float16 v = (_Float16)acc[i][j][r];
                    Y[(size_t)row * 256 + col] = v;
                    if (col >= 192) Tc[(size_t)row * 64 + (col - 192)] = v;
                }
            }
        }
    }
}

// ================= packed pipeline kernels =================
// D2: composeF (weights only)  ||  hist (edst only; cnt zeroed by memset)
__global__ __launch_bounds__(256) void k_composeF_hist(
    const int* __restrict__ edst, int* __restrict__ cnt, unsigned short* __restrict__ rank,
    const float* __restrict__ W0s, const float* __restrict__ W0n, const float* __restrict__ b0,
    const float* __restrict__ W1s, const float* __restrict__ W1n, const float* __restrict__ b1,
    float* __restrict__ C2)
{
    if (blockIdx.x < CF_BLOCKS) {
        compose_first_dev(blockIdx.x, W0s, W0n, b0, W1s, W1n, b1, C2);
    } else {
        int e = (blockIdx.x - CF_BLOCKS) * 256 + threadIdx.x;
        if (e < NE) rank[e] = (unsigned short)atomicAdd(&cnt[edst[e]], 1);
    }
}

// D3: composeM (needs C2)  ||  scanA (needs cnt complete)
__global__ __launch_bounds__(256) void k_composeM_scanA(
    const int* __restrict__ cnt, int* __restrict__ blockSums,
    const float* __restrict__ C2,
    const float* __restrict__ W2s, const float* __restrict__ W2n, const float* __restrict__ b2,
    float* __restrict__ C3)
{
    if (blockIdx.x < CF_BLOCKS) compose_mid_dev(blockIdx.x, C2, W2s, W2n, b2, C3);
    else scan_block_sums_dev(cnt, blockSums, NN, blockIdx.x - CF_BLOCKS);
}

// D4: scanT (needs blockSums) || composeL (needs C3)
__global__ __launch_bounds__(256) void k_scanT_composeL(
    int* __restrict__ blockSums,
    const float* __restrict__ C3, const float* __restrict__ Wfc, const float* __restrict__ bfc,
    float* __restrict__ Vf, _Float16* __restrict__ BT)
{
    if (blockIdx.x == 0) scan_top_dev(blockSums, SCAN_BLOCKS);
    else compose_last_dev(blockIdx.x - 1, C3, Wfc, bfc, Vf, BT);
}

// D5: gemm cols 0..127 (needs BT) || scanF (needs scanT)
__global__ __launch_bounds__(256) void k_gemmA_scanF(
    const int* __restrict__ cnt, const int* __restrict__ blockBase,
    int* __restrict__ offs, float* __restrict__ dinv,
    const float* __restrict__ X, const _Float16* __restrict__ BT,
    _Float16* __restrict__ Y, _Float16* __restrict__ Tc)
{
    if (blockIdx.x < GA_BLOCKS) gemm_y_dev(blockIdx.x, 0, X, BT, Y, Tc, NN);
    else scan_final_dev(cnt, blockBase, offs, dinv, NN, blockIdx.x - GA_BLOCKS);
}

// D6: gemm cols 128..255 + Tc copy || place (needs offs)
__global__ __launch_bounds__(256) void k_gemmB_place(
    const int* __restrict__ esrc, const int* __restrict__ edst,
    const unsigned short* __restrict__ rank, const int* __restrict__ offs,
    unsigned short* __restrict__ csr,
    const float* __restrict__ X, const _Float16* __restrict__ BT,
    _Float16* __restrict__ Y, _Float16* __restrict__ Tc)
{
    if (blockIdx.x < GA_BLOCKS) {
        gemm_y_dev(blockIdx.x, 1, X, BT, Y, Tc, NN);
    } else {
        int e = (blockIdx.x - GA_BLOCKS) * 256 + threadIdx.x;
        if (e < NE) csr[offs[edst[e]] + rank[e]] = (unsigned short)esrc[e];
    }
}

// ================= output-side gather chain =================
// 8 lanes per node, 8-deep edge unroll: up to 8 independent 16B loads in flight
template <bool OUT_F32>
__global__ __launch_bounds__(256) void gather64(
    const _Float16* __restrict__ Tin,       // stride-64 compact rows
    const unsigned short* __restrict__ csr, const int* __restrict__ offs,
    const float* __restrict__ dinv,
    const _Float16* __restrict__ Yadd,      // stride 256, pre-offset to column block
    const float* __restrict__ cvec,         // 64 floats
    void* __restrict__ Tout, int N)
{
    int node = blockIdx.x * 32 + (threadIdx.x >> 3);
    int lane = threadIdx.x & 7;
    if (node >= N) return;
    int beg = offs[node], end = offs[node + 1];
    float acc[8] = {};
    int e = beg;
    for (; e + 7 < end; e += 8) {
        int s0 = csr[e], s1 = csr[e + 1], s2 = csr[e + 2], s3 = csr[e + 3];
        int s4 = csr[e + 4], s5 = csr[e + 5], s6 = csr[e + 6], s7 = csr[e + 7];
        half8 v0 = *(const half8*)(Tin + (size_t)s0 * 64 + lane * 8);
        half8 v1 = *(const half8*)(Tin + (size_t)s1 * 64 + lane * 8);
        half8 v2 = *(const half8*)(Tin + (size_t)s2 * 64 + lane * 8);
        half8 v3 = *(const half8*)(Tin + (size_t)s3 * 64 + lane * 8);
        half8 v4 = *(const half8*)(Tin + (size_t)s4 * 64 + lane * 8);
        half8 v5 = *(const half8*)(Tin + (size_t)s5 * 64 + lane * 8);
        half8 v6 = *(const half8*)(Tin + (size_t)s6 * 64 + lane * 8);
        half8 v7 = *(const half8*)(Tin + (size_t)s7 * 64 + lane * 8);
        #pragma unroll
        for (int j = 0; j < 8; ++j)
            acc[j] += (((float)v0[j] + (float)v1[j]) + ((float)v2[j] + (float)v3[j]))
                    + (((float)v4[j] + (float)v5[j]) + ((float)v6[j] + (float)v7[j]));
    }
    for (; e + 3 < end; e += 4) {
        int s0 = csr[e], s1 = csr[e + 1], s2 = csr[e + 2], s3 = csr[e + 3];
        half8 v0 = *(const half8*)(Tin + (size_t)s0 * 64 + lane * 8);
        half8 v1 = *(const half8*)(Tin + (size_t)s1 * 64 + lane * 8);
        half8 v2 = *(const half8*)(Tin + (size_t)s2 * 64 + lane * 8);
        half8 v3 = *(const half8*)(Tin + (size_t)s3 * 64 + lane * 8);
        #pragma unroll
        for (int j = 0; j < 8; ++j)
            acc[j] += ((float)v0[j] + (float)v1[j]) + ((float)v2[j] + (float)v3[j]);
    }
    for (; e < end; ++e) {
        half8 v = *(const half8*)(Tin + (size_t)csr[e] * 64 + lane * 8);
        #pragma unroll
        for (int j = 0; j < 8; ++j) acc[j] += (float)v[j];
    }
    float sc = dinv[node];
    half8 y = *(const half8*)(Yadd + (size_t)node * 256 + lane * 8);
    if (OUT_F32) {
        float* o = (float*)Tout + (size_t)node * 64 + lane * 8;
        float4 o0, o1;
        o0.x = acc[0] * sc + (float)y[0] + cvec[lane * 8 + 0];
        o0.y = acc[1] * sc + (float)y[1] + cvec[lane * 8 + 1];
        o0.z = acc[2] * sc + (float)y[2] + cvec[lane * 8 + 2];
        o0.w = acc[3] * sc + (float)y[3] + cvec[lane * 8 + 3];
        o1.x = acc[4] * sc + (float)y[4] + cvec[lane * 8 + 4];
        o1.y = acc[5] * sc + (float)y[5] + cvec[lane * 8 + 5];
        o1.z = acc[6] * sc + (float)y[6] + cvec[lane * 8 + 6];
        o1.w = acc[7] * sc + (float)y[7] + cvec[lane * 8 + 7];
        *(float4*)o = o0;
        *(float4*)(o + 4) = o1;
    } else {
        half8 o;
        #pragma unroll
        for (int j = 0; j < 8; ++j)
            o[j] = (_Float16)(acc[j] * sc + (float)y[j] + cvec[lane * 8 + j]);
        *(half8*)((_Float16*)Tout + (size_t)node * 64 + lane * 8) = o;
    }
}

extern "C" void kernel_launch(void* const* d_in, const int* in_sizes, int n_in,
                              void* d_out, int out_size, void* d_ws, size_t ws_size,
                              hipStream_t stream) {
    const float* x    = (const float*)d_in[0];
    const int*   esrc = (const int*)d_in[1];
    const int*   edst = (const int*)d_in[2];
    const float* W0s  = (const float*)d_in[3];
    const float* W0n  = (const float*)d_in[4];
    const float* b0   = (const float*)d_in[5];
    const float* W1s  = (const float*)d_in[6];
    const float* W1n  = (const float*)d_in[7];
    const float* b1   = (const float*)d_in[8];
    const float* W2s  = (const float*)d_in[9];
    const float* W2n  = (const float*)d_in[10];
    const float* b2   = (const float*)d_in[11];
    const float* Wfc  = (const float*)d_in[12];
    const float* bfc  = (const float*)d_in[13];
    float* out = (float*)d_out;

    // ---- workspace layout ----
    _Float16* Y   = (_Float16*)d_ws;                  // N x 256  [Y0|Y1|Y2|Y3]
    _Float16* Ta  = Y + (size_t)NN * 256;             // N x 64
    _Float16* Tb  = Ta + (size_t)NN * 64;             // N x 64
    _Float16* Tc  = Tb + (size_t)NN * 64;             // N x 64 (dense Y3 copy)
    _Float16* BT  = Tc + (size_t)NN * 64;             // 256 x 128
    float* C2     = (float*)(BT + 256 * 128);         // 515 x 256
    float* C3     = C2 + CROWS * 256;                 // 515 x 256
    float* Vf     = C3 + CROWS * 256;                 // 515 x 64
    float* dinv   = Vf + CROWS * 64;                  // N
    int* cnt      = (int*)(dinv + NN);                // N   (memset target)
    int* offs     = cnt + NN;                         // N+1
    int* blockSums = offs + NN + 1;                   // SCAN_BLOCKS
    unsigned short* rank = (unsigned short*)(blockSums + SCAN_BLOCKS);  // E
    unsigned short* csr  = rank + NE;                 // E

    // D1: zero the histogram counters
    hipMemsetAsync(cnt, 0, (size_t)NN * sizeof(int), stream);

    // D2: weight-compose layer0->1  ||  degree histogram (+rank)
    k_composeF_hist<<<CF_BLOCKS + HB, 256, 0, stream>>>(
        edst, cnt, rank, W0s, W0n, b0, W1s, W1n, b1, C2);

    // D3: weight-compose layer2  ||  per-block degree sums
    k_composeM_scanA<<<CF_BLOCKS + SCAN_BLOCKS, 256, 0, stream>>>(
        cnt, blockSums, C2, W2s, W2n, b2, C3);

    // D4: top-level scan || final compose (Vf + BT)
    k_scanT_composeL<<<1 + CL_BLOCKS, 256, 0, stream>>>(
        blockSums, C3, Wfc, bfc, Vf, BT);

    // D5: gemm Y cols 0..127 || final scan (offs, dinv)
    k_gemmA_scanF<<<GA_BLOCKS + SCAN_BLOCKS, 256, 0, stream>>>(
        cnt, blockSums, offs, dinv, x, BT, Y, Tc);

    // D6: gemm Y cols 128..255 (+Tc) || CSR placement
    k_gemmB_place<<<GA_BLOCKS + HB, 256, 0, stream>>>(
        esrc, edst, rank, offs, csr, x, BT, Y, Tc);

    // D7-9: output-side propagation: out = Y0 + c1 + A(Y1 + c2 + A(Y2 + c3 + A*Y3))
    // Plain dispatches: kernel-boundary sync is far cheaper than grid.sync's
    // device-scope fencing on non-coherent per-XCD L2s (round-1 lesson: 859 µs coop).
    const int ggrid = (NN + 31) / 32;
    gather64<false><<<ggrid, 256, 0, stream>>>(
        Tc, csr, offs, dinv, Y + 128, Vf + (size_t)514 * 64, (void*)Ta, NN);
    gather64<false><<<ggrid, 256, 0, stream>>>(
        Ta, csr, offs, dinv, Y + 64, Vf + (size_t)513 * 64, (void*)Tb, NN);
    gather64<true><<<ggrid, 256, 0, stream>>>(
        Tb, csr, offs, dinv, Y, Vf + (size_t)512 * 64, (void*)out, NN);
}

// Round 3
// 265.589 us; speedup vs baseline: 2.8763x; 1.0852x over previous
//
#include <hip/hip_runtime.h>

#define NN 50000
#define NE 800000
#define F_IN 128
#define HID 256
#define N_CLS 64
#define SCAN_BLOCKS ((NN + 255) / 256)   // 196
#define HEPT 4                           // edges per thread in hist/place
#define HB2 ((NE + 256 * HEPT - 1) / (256 * HEPT))   // 782 edge blocks
#define CF_BLOCKS 36                     // compose 515x256 tiles: 9 row x 4 col
#define CL_BLOCKS 9                      // compose 515x64 tiles
#define GA_BLOCKS ((NN + 127) / 128)     // 391 gemm row-blocks
#define CROWS 515                        // basis: X,AX,A2X,A3X (4*128) + 1,d,Ad

typedef _Float16 half8 __attribute__((ext_vector_type(8)));
typedef float f32x4 __attribute__((ext_vector_type(4)));

// ================= affine-map composition =================
__device__ __forceinline__ const float* virtC1_row(int r, const float* W0s,
                                                   const float* W0n, const float* b0) {
    if (r < 0) return nullptr;
    if (r < 128) return W0s + (size_t)r * 256;
    if (r < 256) return W0n + (size_t)(r - 128) * 256;
    if (r == 512) return b0;
    return nullptr;
}

__device__ __forceinline__ int shift_src(int r) {
    if (r >= 128 && r < 512) return r - 128;
    if (r == 513) return 512;
    if (r == 514) return 513;
    return -1;
}

// 32-step flattened compose with register prefetch of next As/Bs tile:
// global-load latency hides under the FMA block (1 block/CU -> no TLP otherwise).
__device__ __forceinline__ void compose_first_dev(
    int bx, const float* __restrict__ W0s, const float* __restrict__ W0n,
    const float* __restrict__ b0,
    const float* __restrict__ B1, const float* __restrict__ B2,
    const float* __restrict__ brow, float* __restrict__ C)
{
    __shared__ float As[64][17];
    __shared__ float Bs[16][64];
    const int tid = threadIdx.x;
    const int tx = tid & 15, ty = tid >> 4;
    const int row0 = (bx % 9) * 64;
    const int col0 = (bx / 9) * 64;
    const int lr = tid >> 2, lc = tid & 3;
    const int br = tid >> 4, bc = tid & 15;

    const int grow = row0 + lr;
    const int srcr0 = (grow < CROWS) ? grow : -1;
    const float* ap0 = virtC1_row(srcr0, W0s, W0n, b0);
    const float* ap1 = virtC1_row(shift_src(grow), W0s, W0n, b0);

    float acc[4][4] = {};

    float4 av = ap0 ? *(const float4*)(ap0 + lc * 4) : make_float4(0.f, 0.f, 0.f, 0.f);
    float4 bv = *(const float4*)(B1 + (size_t)br * 256 + col0 + bc * 4);

    for (int s = 0; s < 32; ++s) {
        As[lr][lc * 4 + 0] = av.x;
        As[lr][lc * 4 + 1] = av.y;
        As[lr][lc * 4 + 2] = av.z;
        As[lr][lc * 4 + 3] = av.w;
        *(float4*)&Bs[br][bc * 4] = bv;
        __syncthreads();
        if (s + 1 < 32) {
            int pass = (s + 1) >> 4;
            int k0 = ((s + 1) & 15) << 4;
            const float* ap = pass ? ap1 : ap0;
            const float* B = pass ? B2 : B1;
            av = ap ? *(const float4*)(ap + k0 + lc * 4) : make_float4(0.f, 0.f, 0.f, 0.f);
            bv = *(const float4*)(B + (size_t)(k0 + br) * 256 + col0 + bc * 4);
        }
        #pragma unroll
        for (int k = 0; k < 16; ++k) {
            float a[4];
            #pragma unroll
            for (int i = 0; i < 4; ++i) a[i] = As[ty * 4 + i][k];
            float4 bb = *(const float4*)&Bs[k][tx * 4];
            const float b[4] = {bb.x, bb.y, bb.z, bb.w};
            #pragma unroll
            for (int i = 0; i < 4; ++i)
                #pragma unroll
                for (int j = 0; j < 4; ++j)
                    acc[i][j] += a[i] * b[j];
        }
        __syncthreads();
    }

    #pragma unroll
    for (int i = 0; i < 4; ++i) {
        int r = row0 + ty * 4 + i;
        if (r < CROWS) {
            #pragma unroll
            for (int j = 0; j < 4; ++j) {
                float v = acc[i][j];
                if (r == 512) v += brow[col0 + tx * 4 + j];
                C[(size_t)r * 256 + col0 + tx * 4 + j] = v;
            }
        }
    }
}

__device__ __forceinline__ void compose_mid_dev(
    int bx, const float* __restrict__ A,
    const float* __restrict__ B1, const float* __restrict__ B2,
    const float* __restrict__ brow, float* __restrict__ C)
{
    __shared__ float As[64][17];
    __shared__ float Bs[16][64];
    const int tid = threadIdx.x;
    const int tx = tid & 15, ty = tid >> 4;
    const int row0 = (bx % 9) * 64;
    const int col0 = (bx / 9) * 64;
    const int lr = tid >> 2, lc = tid & 3;
    const int br = tid >> 4, bc = tid & 15;

    const int grow = row0 + lr;
    const int p0 = (grow < CROWS) ? grow : -1;
    const int p1 = shift_src(grow);

    float acc[4][4] = {};

    float4 av = (p0 >= 0) ? *(const float4*)(A + (size_t)p0 * 256 + lc * 4)
                          : make_float4(0.f, 0.f, 0.f, 0.f);
    float4 bv = *(const float4*)(B1 + (size_t)br * 256 + col0 + bc * 4);

    for (int s = 0; s < 32; ++s) {
        As[lr][lc * 4 + 0] = av.x;
        As[lr][lc * 4 + 1] = av.y;
        As[lr][lc * 4 + 2] = av.z;
        As[lr][lc * 4 + 3] = av.w;
        *(float4*)&Bs[br][bc * 4] = bv;
        __syncthreads();
        if (s + 1 < 32) {
            int pass = (s + 1) >> 4;
            int k0 = ((s + 1) & 15) << 4;
            int p = pass ? p1 : p0;
            const float* B = pass ? B2 : B1;
            av = (p >= 0) ? *(const float4*)(A + (size_t)p * 256 + k0 + lc * 4)
                          : make_float4(0.f, 0.f, 0.f, 0.f);
            bv = *(const float4*)(B + (size_t)(k0 + br) * 256 + col0 + bc * 4);
        }
        #pragma unroll
        for (int k = 0; k < 16; ++k) {
            float a[4];
            #pragma unroll
            for (int i = 0; i < 4; ++i) a[i] = As[ty * 4 + i][k];
            float4 bb = *(const float4*)&Bs[k][tx * 4];
            const float b[4] = {bb.x, bb.y, bb.z, bb.w};
            #pragma unroll
            for (int i = 0; i < 4; ++i)
                #pragma unroll
                for (int j = 0; j < 4; ++j)
                    acc[i][j] += a[i] * b[j];
        }
        __syncthreads();
    }

    #pragma unroll
    for (int i = 0; i < 4; ++i) {
        int r = row0 + ty * 4 + i;
        if (r < CROWS) {
            #pragma unroll
            for (int j = 0; j < 4; ++j) {
                float v = acc[i][j];
                if (r == 512) v += brow[col0 + tx * 4 + j];
                C[(size_t)r * 256 + col0 + tx * 4 + j] = v;
            }
        }
    }
}

__device__ __forceinline__ void compose_last_dev(
    int bx, const float* __restrict__ A, const float* __restrict__ B1,
    const float* __restrict__ brow, float* __restrict__ Vf, _Float16* __restrict__ BT)
{
    __shared__ float As[64][17];
    __shared__ float Bs[16][64];
    const int tid = threadIdx.x;
    const int tx = tid & 15, ty = tid >> 4;
    const int row0 = bx * 64;
    const int lr = tid >> 2, lc = tid & 3;
    const int br = tid >> 4, bc = tid & 15;

    const int grow = row0 + lr;
    const float* ap = (grow < CROWS) ? (A + (size_t)grow * 256) : nullptr;

    float acc[4][4] = {};

    float4 av = ap ? *(const float4*)(ap + lc * 4) : make_float4(0.f, 0.f, 0.f, 0.f);
    float4 bv = *(const float4*)(B1 + (size_t)br * 64 + bc * 4);

    for (int s = 0; s < 16; ++s) {
        As[lr][lc * 4 + 0] = av.x;
        As[lr][lc * 4 + 1] = av.y;
        As[lr][lc * 4 + 2] = av.z;
        As[lr][lc * 4 + 3] = av.w;
        *(float4*)&Bs[br][bc * 4] = bv;
        __syncthreads();
        if (s + 1 < 16) {
            int k0 = (s + 1) << 4;
            av = ap ? *(const float4*)(ap + k0 + lc * 4) : make_float4(0.f, 0.f, 0.f, 0.f);
            bv = *(const float4*)(B1 + (size_t)(k0 + br) * 64 + bc * 4);
        }
        #pragma unroll
        for (int k = 0; k < 16; ++k) {
            float a[4];
            #pragma unroll
            for (int i = 0; i < 4; ++i) a[i] = As[ty * 4 + i][k];
            float4 bb = *(const float4*)&Bs[k][tx * 4];
            const float b[4] = {bb.x, bb.y, bb.z, bb.w};
            #pragma unroll
            for (int i = 0; i < 4; ++i)
                #pragma unroll
                for (int j = 0; j < 4; ++j)
                    acc[i][j] += a[i] * b[j];
        }
        __syncthreads();
    }

    #pragma unroll
    for (int i = 0; i < 4; ++i) {
        int r = row0 + ty * 4 + i;
        if (r < CROWS) {
            #pragma unroll
            for (int j = 0; j < 4; ++j) {
                int c = tx * 4 + j;
                float v = acc[i][j];
                if (r == 512) v += brow[c];
                Vf[(size_t)r * 64 + c] = v;
                if (r < 512)
                    BT[(size_t)((r >> 7) * 64 + c) * 128 + (r & 127)] = (_Float16)v;
            }
        }
    }
}

// ================= scan chain device pieces =================
__device__ __forceinline__ void scan_block_sums_dev(const int* __restrict__ cnt,
                                                    int* __restrict__ blockSums, int n, int bx) {
    __shared__ int s[256];
    int t = threadIdx.x;
    int i = bx * 256 + t;
    s[t] = (i < n) ? cnt[i] : 0;
    __syncthreads();
    for (int off = 128; off > 0; off >>= 1) {
        if (t < off) s[t] += s[t + off];
        __syncthreads();
    }
    if (t == 0) blockSums[bx] = s[0];
}

__device__ __forceinline__ void scan_top_dev(int* __restrict__ blockSums, int nb) {
    __shared__ int s[256];
    int t = threadIdx.x;
    s[t] = (t < nb) ? blockSums[t] : 0;
    __syncthreads();
    for (int off = 1; off < 256; off <<= 1) {
        int v = (t >= off) ? s[t - off] : 0;
        __syncthreads();
        s[t] += v;
        __syncthreads();
    }
    if (t < nb) blockSums[t] = (t > 0) ? s[t - 1] : 0;  // exclusive
}

__device__ __forceinline__ void scan_final_dev(const int* __restrict__ cnt,
                                               const int* __restrict__ blockBase,
                                               int* __restrict__ offs,
                                               float* __restrict__ dinv, int n, int bx) {
    __shared__ int s[256];
    int t = threadIdx.x;
    int i = bx * 256 + t;
    int v = (i < n) ? cnt[i] : 0;
    s[t] = v;
    __syncthreads();
    for (int off = 1; off < 256; off <<= 1) {
        int u = (t >= off) ? s[t - off] : 0;
        __syncthreads();
        s[t] += u;
        __syncthreads();
    }
    if (i < n) {
        offs[i] = blockBase[bx] + s[t] - v;
        dinv[i] = 1.0f / (float)max(v, 1);
    }
    if (i == n - 1) offs[n] = blockBase[bx] + s[t];
}

// ================= Y GEMM device piece =================
__device__ __forceinline__ void gemm_y_dev(
    int bx, int by,
    const float* __restrict__ X, const _Float16* __restrict__ BT,
    _Float16* __restrict__ Y, _Float16* __restrict__ Tc, int N)
{
    constexpr int LP = 40;
    __shared__ _Float16 As[128 * LP];
    __shared__ _Float16 Bs[128 * LP];

    const int tid = threadIdx.x;
    const int wave = tid >> 6;
    const int lane = tid & 63;
    const int l15 = lane & 15;
    const int quad = lane >> 4;
    const int wrow = wave >> 1;
    const int wcol = wave & 1;
    const int m_base = wrow * 64;
    const int n_base = wcol * 64;

    const int row0 = bx * 128;
    const int col0 = by * 128;

    f32x4 acc[4][4] = {};

    for (int k0 = 0; k0 < 128; k0 += 32) {
        #pragma unroll
        for (int r = 0; r < 2; ++r) {
            int idx = r * 256 + tid;
            int row = idx >> 2, ch = idx & 3;
            int gr = row0 + row; if (gr > N - 1) gr = N - 1;
            const float* ap = X + (size_t)gr * 128 + k0 + ch * 8;
            float4 f0 = *(const float4*)ap;
            float4 f1 = *(const float4*)(ap + 4);
            half8 v = { (_Float16)f0.x, (_Float16)f0.y, (_Float16)f0.z, (_Float16)f0.w,
                        (_Float16)f1.x, (_Float16)f1.y, (_Float16)f1.z, (_Float16)f1.w };
            *(half8*)&As[row * LP + ch * 8] = v;
        }
        #pragma unroll
        for (int r = 0; r < 2; ++r) {
            int idx = r * 256 + tid;
            int row = idx >> 2, ch = idx & 3;
            *(half8*)&Bs[row * LP + ch * 8] =
                *(const half8*)(BT + (size_t)(col0 + row) * 128 + k0 + ch * 8);
        }
        __syncthreads();
        half8 af[4], bf[4];
        #pragma unroll
        for (int i = 0; i < 4; ++i)
            af[i] = *(const half8*)&As[(m_base + i * 16 + l15) * LP + quad * 8];
        #pragma unroll
        for (int j = 0; j < 4; ++j)
            bf[j] = *(const half8*)&Bs[(n_base + j * 16 + l15) * LP + quad * 8];
        #pragma unroll
        for (int i = 0; i < 4; ++i)
            #pragma unroll
            for (int j = 0; j < 4; ++j)
                acc[i][j] = __builtin_amdgcn_mfma_f32_16x16x32_f16(af[i], bf[j], acc[i][j], 0, 0, 0);
        __syncthreads();
    }

    #pragma unroll
    for (int i = 0; i < 4; ++i) {
        #pragma unroll
        for (int j = 0; j < 4; ++j) {
            int col = col0 + n_base + j * 16 + l15;
            #pragma unroll
            for (int r = 0; r < 4; ++r) {
                int row = row0 + m_base + i * 16 + quad * 4 + r;
                if (row < N) {
                    _Float16 v = (_Float16)acc[i][j][r];
                    Y[(size_t)row * 256 + col] = v;
                    if (col >= 192) Tc[(size_t)row * 64 + (col - 192)] = v;
                }
            }
        }
    }
}

// ================= packed pipeline kernels =================
// D2: composeF (weights only)  ||  hist (edst only; cnt zeroed by memset)
// hist: 4 edges/thread, 4 independent returning atomics in flight (latency-bound fix)
__global__ __launch_bounds__(256) void k_composeF_hist(
    const int* __restrict__ edst, int* __restrict__ cnt, unsigned short* __restrict__ rank,
    const float* __restrict__ W0s, const float* __restrict__ W0n, const float* __restrict__ b0,
    const float* __restrict__ W1s, const float* __restrict__ W1n, const float* __restrict__ b1,
    float* __restrict__ C2)
{
    if (blockIdx.x < CF_BLOCKS) {
        compose_first_dev(blockIdx.x, W0s, W0n, b0, W1s, W1n, b1, C2);
    } else {
        int base = (blockIdx.x - CF_BLOCKS) * (256 * HEPT) + threadIdx.x;
        int d[HEPT];
        #pragma unroll
        for (int k = 0; k < HEPT; ++k) {
            int e = base + k * 256;
            d[k] = (e < NE) ? edst[e] : -1;
        }
        #pragma unroll
        for (int k = 0; k < HEPT; ++k) {
            int e = base + k * 256;
            if (d[k] >= 0) rank[e] = (unsigned short)atomicAdd(&cnt[d[k]], 1);
        }
    }
}

// D3: composeM (needs C2)  ||  scanA (needs cnt complete)
__global__ __launch_bounds__(256) void k_composeM_scanA(
    const int* __restrict__ cnt, int* __restrict__ blockSums,
    const float* __restrict__ C2,
    const float* __restrict__ W2s, const float* __restrict__ W2n, const float* __restrict__ b2,
    float* __restrict__ C3)
{
    if (blockIdx.x < CF_BLOCKS) compose_mid_dev(blockIdx.x, C2, W2s, W2n, b2, C3);
    else scan_block_sums_dev(cnt, blockSums, NN, blockIdx.x - CF_BLOCKS);
}

// D4: scanT (needs blockSums) || composeL (needs C3)
__global__ __launch_bounds__(256) void k_scanT_composeL(
    int* __restrict__ blockSums,
    const float* __restrict__ C3, const float* __restrict__ Wfc, const float* __restrict__ bfc,
    float* __restrict__ Vf, _Float16* __restrict__ BT)
{
    if (blockIdx.x == 0) scan_top_dev(blockSums, SCAN_BLOCKS);
    else compose_last_dev(blockIdx.x - 1, C3, Wfc, bfc, Vf, BT);
}

// D5: gemm cols 0..127 (needs BT) || scanF (needs scanT)
__global__ __launch_bounds__(256) void k_gemmA_scanF(
    const int* __restrict__ cnt, const int* __restrict__ blockBase,
    int* __restrict__ offs, float* __restrict__ dinv,
    const float* __restrict__ X, const _Float16* __restrict__ BT,
    _Float16* __restrict__ Y, _Float16* __restrict__ Tc)
{
    if (blockIdx.x < GA_BLOCKS) gemm_y_dev(blockIdx.x, 0, X, BT, Y, Tc, NN);
    else scan_final_dev(cnt, blockBase, offs, dinv, NN, blockIdx.x - GA_BLOCKS);
}

// D6: gemm cols 128..255 + Tc copy || place (needs offs); place gets 4-deep ILP too
__global__ __launch_bounds__(256) void k_gemmB_place(
    const int* __restrict__ esrc, const int* __restrict__ edst,
    const unsigned short* __restrict__ rank, const int* __restrict__ offs,
    unsigned short* __restrict__ csr,
    const float* __restrict__ X, const _Float16* __restrict__ BT,
    _Float16* __restrict__ Y, _Float16* __restrict__ Tc)
{
    if (blockIdx.x < GA_BLOCKS) {
        gemm_y_dev(blockIdx.x, 1, X, BT, Y, Tc, NN);
    } else {
        int base = (blockIdx.x - GA_BLOCKS) * (256 * HEPT) + threadIdx.x;
        int d[HEPT], s[HEPT], r[HEPT];
        #pragma unroll
        for (int k = 0; k < HEPT; ++k) {
            int e = base + k * 256;
            if (e < NE) { d[k] = edst[e]; s[k] = esrc[e]; r[k] = rank[e]; }
            else d[k] = -1;
        }
        #pragma unroll
        for (int k = 0; k < HEPT; ++k) {
            if (d[k] >= 0) csr[offs[d[k]] + r[k]] = (unsigned short)s[k];
        }
    }
}

// ================= output-side gather chain =================
// 8 lanes per node, 8-deep edge unroll: up to 8 independent 16B loads in flight
template <bool OUT_F32>
__global__ __launch_bounds__(256) void gather64(
    const _Float16* __restrict__ Tin,       // stride-64 compact rows
    const unsigned short* __restrict__ csr, const int* __restrict__ offs,
    const float* __restrict__ dinv,
    const _Float16* __restrict__ Yadd,      // stride 256, pre-offset to column block
    const float* __restrict__ cvec,         // 64 floats
    void* __restrict__ Tout, int N)
{
    int node = blockIdx.x * 32 + (threadIdx.x >> 3);
    int lane = threadIdx.x & 7;
    if (node >= N) return;
    int beg = offs[node], end = offs[node + 1];
    float acc[8] = {};
    int e = beg;
    for (; e + 7 < end; e += 8) {
        int s0 = csr[e], s1 = csr[e + 1], s2 = csr[e + 2], s3 = csr[e + 3];
        int s4 = csr[e + 4], s5 = csr[e + 5], s6 = csr[e + 6], s7 = csr[e + 7];
        half8 v0 = *(const half8*)(Tin + (size_t)s0 * 64 + lane * 8);
        half8 v1 = *(const half8*)(Tin + (size_t)s1 * 64 + lane * 8);
        half8 v2 = *(const half8*)(Tin + (size_t)s2 * 64 + lane * 8);
        half8 v3 = *(const half8*)(Tin + (size_t)s3 * 64 + lane * 8);
        half8 v4 = *(const half8*)(Tin + (size_t)s4 * 64 + lane * 8);
        half8 v5 = *(const half8*)(Tin + (size_t)s5 * 64 + lane * 8);
        half8 v6 = *(const half8*)(Tin + (size_t)s6 * 64 + lane * 8);
        half8 v7 = *(const half8*)(Tin + (size_t)s7 * 64 + lane * 8);
        #pragma unroll
        for (int j = 0; j < 8; ++j)
            acc[j] += (((float)v0[j] + (float)v1[j]) + ((float)v2[j] + (float)v3[j]))
                    + (((float)v4[j] + (float)v5[j]) + ((float)v6[j] + (float)v7[j]));
    }
    for (; e + 3 < end; e += 4) {
        int s0 = csr[e], s1 = csr[e + 1], s2 = csr[e + 2], s3 = csr[e + 3];
        half8 v0 = *(const half8*)(Tin + (size_t)s0 * 64 + lane * 8);
        half8 v1 = *(const half8*)(Tin + (size_t)s1 * 64 + lane * 8);
        half8 v2 = *(const half8*)(Tin + (size_t)s2 * 64 + lane * 8);
        half8 v3 = *(const half8*)(Tin + (size_t)s3 * 64 + lane * 8);
        #pragma unroll
        for (int j = 0; j < 8; ++j)
            acc[j] += ((float)v0[j] + (float)v1[j]) + ((float)v2[j] + (float)v3[j]);
    }
    for (; e < end; ++e) {
        half8 v = *(const half8*)(Tin + (size_t)csr[e] * 64 + lane * 8);
        #pragma unroll
        for (int j = 0; j < 8; ++j) acc[j] += (float)v[j];
    }
    float sc = dinv[node];
    half8 y = *(const half8*)(Yadd + (size_t)node * 256 + lane * 8);
    if (OUT_F32) {
        float* o = (float*)Tout + (size_t)node * 64 + lane * 8;
        float4 o0, o1;
        o0.x = acc[0] * sc + (float)y[0] + cvec[lane * 8 + 0];
        o0.y = acc[1] * sc + (float)y[1] + cvec[lane * 8 + 1];
        o0.z = acc[2] * sc + (float)y[2] + cvec[lane * 8 + 2];
        o0.w = acc[3] * sc + (float)y[3] + cvec[lane * 8 + 3];
        o1.x = acc[4] * sc + (float)y[4] + cvec[lane * 8 + 4];
        o1.y = acc[5] * sc + (float)y[5] + cvec[lane * 8 + 5];
        o1.z = acc[6] * sc + (float)y[6] + cvec[lane * 8 + 6];
        o1.w = acc[7] * sc + (float)y[7] + cvec[lane * 8 + 7];
        *(float4*)o = o0;
        *(float4*)(o + 4) = o1;
    } else {
        half8 o;
        #pragma unroll
        for (int j = 0; j < 8; ++j)
            o[j] = (_Float16)(acc[j] * sc + (float)y[j] + cvec[lane * 8 + j]);
        *(half8*)((_Float16*)Tout + (size_t)node * 64 + lane * 8) = o;
    }
}

extern "C" void kernel_launch(void* const* d_in, const int* in_sizes, int n_in,
                              void* d_out, int out_size, void* d_ws, size_t ws_size,
                              hipStream_t stream) {
    const float* x    = (const float*)d_in[0];
    const int*   esrc = (const int*)d_in[1];
    const int*   edst = (const int*)d_in[2];
    const float* W0s  = (const float*)d_in[3];
    const float* W0n  = (const float*)d_in[4];
    const float* b0   = (const float*)d_in[5];
    const float* W1s  = (const float*)d_in[6];
    const float* W1n  = (const float*)d_in[7];
    const float* b1   = (const float*)d_in[8];
    const float* W2s  = (const float*)d_in[9];
    const float* W2n  = (const float*)d_in[10];
    const float* b2   = (const float*)d_in[11];
    const float* Wfc  = (const float*)d_in[12];
    const float* bfc  = (const float*)d_in[13];
    float* out = (float*)d_out;

    // ---- workspace layout ----
    _Float16* Y   = (_Float16*)d_ws;                  // N x 256  [Y0|Y1|Y2|Y3]
    _Float16* Ta  = Y + (size_t)NN * 256;             // N x 64
    _Float16* Tb  = Ta + (size_t)NN * 64;             // N x 64
    _Float16* Tc  = Tb + (size_t)NN * 64;             // N x 64 (dense Y3 copy)
    _Float16* BT  = Tc + (size_t)NN * 64;             // 256 x 128
    float* C2     = (float*)(BT + 256 * 128);         // 515 x 256
    float* C3     = C2 + CROWS * 256;                 // 515 x 256
    float* Vf     = C3 + CROWS * 256;                 // 515 x 64
    float* dinv   = Vf + CROWS * 64;                  // N
    int* cnt      = (int*)(dinv + NN);                // N   (memset target)
    int* offs     = cnt + NN;                         // N+1
    int* blockSums = offs + NN + 1;                   // SCAN_BLOCKS
    unsigned short* rank = (unsigned short*)(blockSums + SCAN_BLOCKS);  // E
    unsigned short* csr  = rank + NE;                 // E

    // D1: zero the histogram counters
    hipMemsetAsync(cnt, 0, (size_t)NN * sizeof(int), stream);

    // D2: weight-compose layer0->1  ||  degree histogram (+rank), 4 edges/thread
    k_composeF_hist<<<CF_BLOCKS + HB2, 256, 0, stream>>>(
        edst, cnt, rank, W0s, W0n, b0, W1s, W1n, b1, C2);

    // D3: weight-compose layer2  ||  per-block degree sums
    k_composeM_scanA<<<CF_BLOCKS + SCAN_BLOCKS, 256, 0, stream>>>(
        cnt, blockSums, C2, W2s, W2n, b2, C3);

    // D4: top-level scan || final compose (Vf + BT)
    k_scanT_composeL<<<1 + CL_BLOCKS, 256, 0, stream>>>(
        blockSums, C3, Wfc, bfc, Vf, BT);

    // D5: gemm Y cols 0..127 || final scan (offs, dinv)
    k_gemmA_scanF<<<GA_BLOCKS + SCAN_BLOCKS, 256, 0, stream>>>(
        cnt, blockSums, offs, dinv, x, BT, Y, Tc);

    // D6: gemm Y cols 128..255 (+Tc) || CSR placement, 4 edges/thread
    k_gemmB_place<<<GA_BLOCKS + HB2, 256, 0, stream>>>(
        esrc, edst, rank, offs, csr, x, BT, Y, Tc);

    // D7-9: output-side propagation: out = Y0 + c1 + A(Y1 + c2 + A(Y2 + c3 + A*Y3))
    // Plain dispatches: kernel-boundary sync is far cheaper than grid.sync's
    // device-scope fencing on non-coherent per-XCD L2s (round-1 lesson: 859 µs coop).
    const int ggrid = (NN + 31) / 32;
    gather64<false><<<ggrid, 256, 0, stream>>>(
        Tc, csr, offs, dinv, Y + 128, Vf + (size_t)514 * 64, (void*)Ta, NN);
    gather64<false><<<ggrid, 256, 0, stream>>>(
        Ta, csr, offs, dinv, Y + 64, Vf + (size_t)513 * 64, (void*)Tb, NN);
    gather64<true><<<ggrid, 256, 0, stream>>>(
        Tb, csr, offs, dinv, Y, Vf + (size_t)512 * 64, (void*)out, NN);
}

// Round 4
// 260.285 us; speedup vs baseline: 2.9349x; 1.0204x over previous
//
#include <hip/hip_runtime.h>

#define NN 50000
#define NE 800000
#define NE_HALF 400000
#define F_IN 128
#define HID 256
#define N_CLS 64
#define SCAN_BLOCKS ((NN + 255) / 256)   // 196
#define HEPT 4                           // edges per thread in hist/place
#define HB2 ((NE + 256 * HEPT - 1) / (256 * HEPT))        // 782 edge blocks (place)
#define HBH ((NE_HALF + 256 * HEPT - 1) / (256 * HEPT))   // 391 edge blocks (hist half)
#define CF_BLOCKS 36                     // compose 515x256 tiles: 9 row x 4 col
#define CL_BLOCKS 9                      // compose 515x64 tiles
#define GA_BLOCKS ((NN + 127) / 128)     // 391 gemm row-blocks
#define CROWS 515                        // basis: X,AX,A2X,A3X (4*128) + 1,d,Ad

typedef _Float16 half8 __attribute__((ext_vector_type(8)));
typedef float f32x4 __attribute__((ext_vector_type(4)));

// ================= affine-map composition =================
__device__ __forceinline__ const float* virtC1_row(int r, const float* W0s,
                                                   const float* W0n, const float* b0) {
    if (r < 0) return nullptr;
    if (r < 128) return W0s + (size_t)r * 256;
    if (r < 256) return W0n + (size_t)(r - 128) * 256;
    if (r == 512) return b0;
    return nullptr;
}

__device__ __forceinline__ int shift_src(int r) {
    if (r >= 128 && r < 512) return r - 128;
    if (r == 513) return 512;
    if (r == 514) return 513;
    return -1;
}

// 32-step flattened compose with register prefetch of next As/Bs tile:
// global-load latency hides under the FMA block (1 block/CU -> no TLP otherwise).
__device__ __forceinline__ void compose_first_dev(
    int bx, const float* __restrict__ W0s, const float* __restrict__ W0n,
    const float* __restrict__ b0,
    const float* __restrict__ B1, const float* __restrict__ B2,
    const float* __restrict__ brow, float* __restrict__ C)
{
    __shared__ float As[64][17];
    __shared__ float Bs[16][64];
    const int tid = threadIdx.x;
    const int tx = tid & 15, ty = tid >> 4;
    const int row0 = (bx % 9) * 64;
    const int col0 = (bx / 9) * 64;
    const int lr = tid >> 2, lc = tid & 3;
    const int br = tid >> 4, bc = tid & 15;

    const int grow = row0 + lr;
    const int srcr0 = (grow < CROWS) ? grow : -1;
    const float* ap0 = virtC1_row(srcr0, W0s, W0n, b0);
    const float* ap1 = virtC1_row(shift_src(grow), W0s, W0n, b0);

    float acc[4][4] = {};

    float4 av = ap0 ? *(const float4*)(ap0 + lc * 4) : make_float4(0.f, 0.f, 0.f, 0.f);
    float4 bv = *(const float4*)(B1 + (size_t)br * 256 + col0 + bc * 4);

    for (int s = 0; s < 32; ++s) {
        As[lr][lc * 4 + 0] = av.x;
        As[lr][lc * 4 + 1] = av.y;
        As[lr][lc * 4 + 2] = av.z;
        As[lr][lc * 4 + 3] = av.w;
        *(float4*)&Bs[br][bc * 4] = bv;
        __syncthreads();
        if (s + 1 < 32) {
            int pass = (s + 1) >> 4;
            int k0 = ((s + 1) & 15) << 4;
            const float* ap = pass ? ap1 : ap0;
            const float* B = pass ? B2 : B1;
            av = ap ? *(const float4*)(ap + k0 + lc * 4) : make_float4(0.f, 0.f, 0.f, 0.f);
            bv = *(const float4*)(B + (size_t)(k0 + br) * 256 + col0 + bc * 4);
        }
        #pragma unroll
        for (int k = 0; k < 16; ++k) {
            float a[4];
            #pragma unroll
            for (int i = 0; i < 4; ++i) a[i] = As[ty * 4 + i][k];
            float4 bb = *(const float4*)&Bs[k][tx * 4];
            const float b[4] = {bb.x, bb.y, bb.z, bb.w};
            #pragma unroll
            for (int i = 0; i < 4; ++i)
                #pragma unroll
                for (int j = 0; j < 4; ++j)
                    acc[i][j] += a[i] * b[j];
        }
        __syncthreads();
    }

    #pragma unroll
    for (int i = 0; i < 4; ++i) {
        int r = row0 + ty * 4 + i;
        if (r < CROWS) {
            #pragma unroll
            for (int j = 0; j < 4; ++j) {
                float v = acc[i][j];
                if (r == 512) v += brow[col0 + tx * 4 + j];
                C[(size_t)r * 256 + col0 + tx * 4 + j] = v;
            }
        }
    }
}

__device__ __forceinline__ void compose_mid_dev(
    int bx, const float* __restrict__ A,
    const float* __restrict__ B1, const float* __restrict__ B2,
    const float* __restrict__ brow, float* __restrict__ C)
{
    __shared__ float As[64][17];
    __shared__ float Bs[16][64];
    const int tid = threadIdx.x;
    const int tx = tid & 15, ty = tid >> 4;
    const int row0 = (bx % 9) * 64;
    const int col0 = (bx / 9) * 64;
    const int lr = tid >> 2, lc = tid & 3;
    const int br = tid >> 4, bc = tid & 15;

    const int grow = row0 + lr;
    const int p0 = (grow < CROWS) ? grow : -1;
    const int p1 = shift_src(grow);

    float acc[4][4] = {};

    float4 av = (p0 >= 0) ? *(const float4*)(A + (size_t)p0 * 256 + lc * 4)
                          : make_float4(0.f, 0.f, 0.f, 0.f);
    float4 bv = *(const float4*)(B1 + (size_t)br * 256 + col0 + bc * 4);

    for (int s = 0; s < 32; ++s) {
        As[lr][lc * 4 + 0] = av.x;
        As[lr][lc * 4 + 1] = av.y;
        As[lr][lc * 4 + 2] = av.z;
        As[lr][lc * 4 + 3] = av.w;
        *(float4*)&Bs[br][bc * 4] = bv;
        __syncthreads();
        if (s + 1 < 32) {
            int pass = (s + 1) >> 4;
            int k0 = ((s + 1) & 15) << 4;
            int p = pass ? p1 : p0;
            const float* B = pass ? B2 : B1;
            av = (p >= 0) ? *(const float4*)(A + (size_t)p * 256 + k0 + lc * 4)
                          : make_float4(0.f, 0.f, 0.f, 0.f);
            bv = *(const float4*)(B + (size_t)(k0 + br) * 256 + col0 + bc * 4);
        }
        #pragma unroll
        for (int k = 0; k < 16; ++k) {
            float a[4];
            #pragma unroll
            for (int i = 0; i < 4; ++i) a[i] = As[ty * 4 + i][k];
            float4 bb = *(const float4*)&Bs[k][tx * 4];
            const float b[4] = {bb.x, bb.y, bb.z, bb.w};
            #pragma unroll
            for (int i = 0; i < 4; ++i)
                #pragma unroll
                for (int j = 0; j < 4; ++j)
                    acc[i][j] += a[i] * b[j];
        }
        __syncthreads();
    }

    #pragma unroll
    for (int i = 0; i < 4; ++i) {
        int r = row0 + ty * 4 + i;
        if (r < CROWS) {
            #pragma unroll
            for (int j = 0; j < 4; ++j) {
                float v = acc[i][j];
                if (r == 512) v += brow[col0 + tx * 4 + j];
                C[(size_t)r * 256 + col0 + tx * 4 + j] = v;
            }
        }
    }
}

__device__ __forceinline__ void compose_last_dev(
    int bx, const float* __restrict__ A, const float* __restrict__ B1,
    const float* __restrict__ brow, float* __restrict__ Vf, _Float16* __restrict__ BT)
{
    __shared__ float As[64][17];
    __shared__ float Bs[16][64];
    const int tid = threadIdx.x;
    const int tx = tid & 15, ty = tid >> 4;
    const int row0 = bx * 64;
    const int lr = tid >> 2, lc = tid & 3;
    const int br = tid >> 4, bc = tid & 15;

    const int grow = row0 + lr;
    const float* ap = (grow < CROWS) ? (A + (size_t)grow * 256) : nullptr;

    float acc[4][4] = {};

    float4 av = ap ? *(const float4*)(ap + lc * 4) : make_float4(0.f, 0.f, 0.f, 0.f);
    float4 bv = *(const float4*)(B1 + (size_t)br * 64 + bc * 4);

    for (int s = 0; s < 16; ++s) {
        As[lr][lc * 4 + 0] = av.x;
        As[lr][lc * 4 + 1] = av.y;
        As[lr][lc * 4 + 2] = av.z;
        As[lr][lc * 4 + 3] = av.w;
        *(float4*)&Bs[br][bc * 4] = bv;
        __syncthreads();
        if (s + 1 < 16) {
            int k0 = (s + 1) << 4;
            av = ap ? *(const float4*)(ap + k0 + lc * 4) : make_float4(0.f, 0.f, 0.f, 0.f);
            bv = *(const float4*)(B1 + (size_t)(k0 + br) * 64 + bc * 4);
        }
        #pragma unroll
        for (int k = 0; k < 16; ++k) {
            float a[4];
            #pragma unroll
            for (int i = 0; i < 4; ++i) a[i] = As[ty * 4 + i][k];
            float4 bb = *(const float4*)&Bs[k][tx * 4];
            const float b[4] = {bb.x, bb.y, bb.z, bb.w};
            #pragma unroll
            for (int i = 0; i < 4; ++i)
                #pragma unroll
                for (int j = 0; j < 4; ++j)
                    acc[i][j] += a[i] * b[j];
        }
        __syncthreads();
    }

    #pragma unroll
    for (int i = 0; i < 4; ++i) {
        int r = row0 + ty * 4 + i;
        if (r < CROWS) {
            #pragma unroll
            for (int j = 0; j < 4; ++j) {
                int c = tx * 4 + j;
                float v = acc[i][j];
                if (r == 512) v += brow[c];
                Vf[(size_t)r * 64 + c] = v;
                if (r < 512)
                    BT[(size_t)((r >> 7) * 64 + c) * 128 + (r & 127)] = (_Float16)v;
            }
        }
    }
}

// ================= hist (half-range) =================
__device__ __forceinline__ void hist_dev(int bx, int start, int count,
                                         const int* __restrict__ edst,
                                         int* __restrict__ cnt,
                                         unsigned short* __restrict__ rank) {
    int base = start + bx * (256 * HEPT) + threadIdx.x;
    int lim = start + count;
    int d[HEPT];
    #pragma unroll
    for (int k = 0; k < HEPT; ++k) {
        int e = base + k * 256;
        d[k] = (e < lim) ? edst[e] : -1;
    }
    #pragma unroll
    for (int k = 0; k < HEPT; ++k) {
        int e = base + k * 256;
        if (d[k] >= 0) rank[e] = (unsigned short)atomicAdd(&cnt[d[k]], 1);
    }
}

// ================= scan chain device pieces =================
__device__ __forceinline__ void scan_block_sums_dev(const int* __restrict__ cnt,
                                                    int* __restrict__ blockSums, int n, int bx) {
    __shared__ int s[256];
    int t = threadIdx.x;
    int i = bx * 256 + t;
    s[t] = (i < n) ? cnt[i] : 0;
    __syncthreads();
    for (int off = 128; off > 0; off >>= 1) {
        if (t < off) s[t] += s[t + off];
        __syncthreads();
    }
    if (t == 0) blockSums[bx] = s[0];
}

// scan_final with inline top-level scan of raw blockSums (removes scanT dispatch)
__device__ __forceinline__ void scan_final2_dev(const int* __restrict__ cnt,
                                                const int* __restrict__ blockSums,
                                                int* __restrict__ offs,
                                                float* __restrict__ dinv, int n, int bx) {
    __shared__ int s[256];
    __shared__ int base_sh;
    int t = threadIdx.x;
    // top-level inclusive scan of the 196 block sums, pick prefix for bx
    s[t] = (t < SCAN_BLOCKS) ? blockSums[t] : 0;
    __syncthreads();
    for (int off = 1; off < 256; off <<= 1) {
        int v = (t >= off) ? s[t - off] : 0;
        __syncthreads();
        s[t] += v;
        __syncthreads();
    }
    if (t == 0) base_sh = (bx > 0) ? s[bx - 1] : 0;
    __syncthreads();
    int base = base_sh;
    __syncthreads();
    // local scan
    int i = bx * 256 + t;
    int v = (i < n) ? cnt[i] : 0;
    s[t] = v;
    __syncthreads();
    for (int off = 1; off < 256; off <<= 1) {
        int u = (t >= off) ? s[t - off] : 0;
        __syncthreads();
        s[t] += u;
        __syncthreads();
    }
    if (i < n) {
        offs[i] = base + s[t] - v;
        dinv[i] = 1.0f / (float)max(v, 1);
    }
    if (i == n - 1) offs[n] = base + s[t];
}

// ================= Y GEMM device piece =================
__device__ __forceinline__ void gemm_y_dev(
    int bx, int by,
    const float* __restrict__ X, const _Float16* __restrict__ BT,
    _Float16* __restrict__ Y, _Float16* __restrict__ Tc, int N)
{
    constexpr int LP = 40;
    __shared__ _Float16 As[128 * LP];
    __shared__ _Float16 Bs[128 * LP];

    const int tid = threadIdx.x;
    const int wave = tid >> 6;
    const int lane = tid & 63;
    const int l15 = lane & 15;
    const int quad = lane >> 4;
    const int wrow = wave >> 1;
    const int wcol = wave & 1;
    const int m_base = wrow * 64;
    const int n_base = wcol * 64;

    const int row0 = bx * 128;
    const int col0 = by * 128;

    f32x4 acc[4][4] = {};

    for (int k0 = 0; k0 < 128; k0 += 32) {
        #pragma unroll
        for (int r = 0; r < 2; ++r) {
            int idx = r * 256 + tid;
            int row = idx >> 2, ch = idx & 3;
            int gr = row0 + row; if (gr > N - 1) gr = N - 1;
            const float* ap = X + (size_t)gr * 128 + k0 + ch * 8;
            float4 f0 = *(const float4*)ap;
            float4 f1 = *(const float4*)(ap + 4);
            half8 v = { (_Float16)f0.x, (_Float16)f0.y, (_Float16)f0.z, (_Float16)f0.w,
                        (_Float16)f1.x, (_Float16)f1.y, (_Float16)f1.z, (_Float16)f1.w };
            *(half8*)&As[row * LP + ch * 8] = v;
        }
        #pragma unroll
        for (int r = 0; r < 2; ++r) {
            int idx = r * 256 + tid;
            int row = idx >> 2, ch = idx & 3;
            *(half8*)&Bs[row * LP + ch * 8] =
                *(const half8*)(BT + (size_t)(col0 + row) * 128 + k0 + ch * 8);
        }
        __syncthreads();
        half8 af[4], bf[4];
        #pragma unroll
        for (int i = 0; i < 4; ++i)
            af[i] = *(const half8*)&As[(m_base + i * 16 + l15) * LP + quad * 8];
        #pragma unroll
        for (int j = 0; j < 4; ++j)
            bf[j] = *(const half8*)&Bs[(n_base + j * 16 + l15) * LP + quad * 8];
        #pragma unroll
        for (int i = 0; i < 4; ++i)
            #pragma unroll
            for (int j = 0; j < 4; ++j)
                acc[i][j] = __builtin_amdgcn_mfma_f32_16x16x32_f16(af[i], bf[j], acc[i][j], 0, 0, 0);
        __syncthreads();
    }

    #pragma unroll
    for (int i = 0; i < 4; ++i) {
        #pragma unroll
        for (int j = 0; j < 4; ++j) {
            int col = col0 + n_base + j * 16 + l15;
            #pragma unroll
            for (int r = 0; r < 4; ++r) {
                int row = row0 + m_base + i * 16 + quad * 4 + r;
                if (row < N) {
                    _Float16 v = (_Float16)acc[i][j][r];
                    Y[(size_t)row * 256 + col] = v;
                    if (col >= 192) Tc[(size_t)row * 64 + (col - 192)] = v;
                }
            }
        }
    }
}

// ================= packed pipeline kernels =================
// D2: composeF || hist first half (fabric-bound atomics hide under VALU-bound compose)
__global__ __launch_bounds__(256) void k_composeF_hist(
    const int* __restrict__ edst, int* __restrict__ cnt, unsigned short* __restrict__ rank,
    const float* __restrict__ W0s, const float* __restrict__ W0n, const float* __restrict__ b0,
    const float* __restrict__ W1s, const float* __restrict__ W1n, const float* __restrict__ b1,
    float* __restrict__ C2)
{
    if (blockIdx.x < CF_BLOCKS) {
        compose_first_dev(blockIdx.x, W0s, W0n, b0, W1s, W1n, b1, C2);
    } else {
        hist_dev(blockIdx.x - CF_BLOCKS, 0, NE_HALF, edst, cnt, rank);
    }
}

// D3: composeM (needs C2) || hist second half
__global__ __launch_bounds__(256) void k_composeM_hist2(
    const int* __restrict__ edst, int* __restrict__ cnt, unsigned short* __restrict__ rank,
    const float* __restrict__ C2,
    const float* __restrict__ W2s, const float* __restrict__ W2n, const float* __restrict__ b2,
    float* __restrict__ C3)
{
    if (blockIdx.x < CF_BLOCKS) compose_mid_dev(blockIdx.x, C2, W2s, W2n, b2, C3);
    else hist_dev(blockIdx.x - CF_BLOCKS, NE_HALF, NE - NE_HALF, edst, cnt, rank);
}

// D4: composeL (needs C3) || scanA (needs full cnt)
__global__ __launch_bounds__(256) void k_composeL_scanA(
    const int* __restrict__ cnt, int* __restrict__ blockSums,
    const float* __restrict__ C3, const float* __restrict__ Wfc, const float* __restrict__ bfc,
    float* __restrict__ Vf, _Float16* __restrict__ BT)
{
    if (blockIdx.x < CL_BLOCKS) compose_last_dev(blockIdx.x, C3, Wfc, bfc, Vf, BT);
    else scan_block_sums_dev(cnt, blockSums, NN, blockIdx.x - CL_BLOCKS);
}

// D5: gemm cols 0..127 (needs BT) || scanF w/ inline top scan (needs blockSums)
__global__ __launch_bounds__(256) void k_gemmA_scanF(
    const int* __restrict__ cnt, const int* __restrict__ blockSums,
    int* __restrict__ offs, float* __restrict__ dinv,
    const float* __restrict__ X, const _Float16* __restrict__ BT,
    _Float16* __restrict__ Y, _Float16* __restrict__ Tc)
{
    if (blockIdx.x < GA_BLOCKS) gemm_y_dev(blockIdx.x, 0, X, BT, Y, Tc, NN);
    else scan_final2_dev(cnt, blockSums, offs, dinv, NN, blockIdx.x - GA_BLOCKS);
}

// D6: gemm cols 128..255 + Tc copy || place (needs offs); place gets 4-deep ILP too
__global__ __launch_bounds__(256) void k_gemmB_place(
    const int* __restrict__ esrc, const int* __restrict__ edst,
    const unsigned short* __restrict__ rank, const int* __restrict__ offs,
    unsigned short* __restrict__ csr,
    const float* __restrict__ X, const _Float16* __restrict__ BT,
    _Float16* __restrict__ Y, _Float16* __restrict__ Tc)
{
    if (blockIdx.x < GA_BLOCKS) {
        gemm_y_dev(blockIdx.x, 1, X, BT, Y, Tc, NN);
    } else {
        int base = (blockIdx.x - GA_BLOCKS) * (256 * HEPT) + threadIdx.x;
        int d[HEPT], s[HEPT], r[HEPT];
        #pragma unroll
        for (int k = 0; k < HEPT; ++k) {
            int e = base + k * 256;
            if (e < NE) { d[k] = edst[e]; s[k] = esrc[e]; r[k] = rank[e]; }
            else d[k] = -1;
        }
        #pragma unroll
        for (int k = 0; k < HEPT; ++k) {
            if (d[k] >= 0) csr[offs[d[k]] + r[k]] = (unsigned short)s[k];
        }
    }
}

// ================= output-side gather chain =================
// 8 lanes per node, 8-deep edge unroll: up to 8 independent 16B loads in flight
template <bool OUT_F32>
__global__ __launch_bounds__(256) void gather64(
    const _Float16* __restrict__ Tin,       // stride-64 compact rows
    const unsigned short* __restrict__ csr, const int* __restrict__ offs,
    const float* __restrict__ dinv,
    const _Float16* __restrict__ Yadd,      // stride 256, pre-offset to column block
    const float* __restrict__ cvec,         // 64 floats
    void* __restrict__ Tout, int N)
{
    int node = blockIdx.x * 32 + (threadIdx.x >> 3);
    int lane = threadIdx.x & 7;
    if (node >= N) return;
    int beg = offs[node], end = offs[node + 1];
    float acc[8] = {};
    int e = beg;
    for (; e + 7 < end; e += 8) {
        int s0 = csr[e], s1 = csr[e + 1], s2 = csr[e + 2], s3 = csr[e + 3];
        int s4 = csr[e + 4], s5 = csr[e + 5], s6 = csr[e + 6], s7 = csr[e + 7];
        half8 v0 = *(const half8*)(Tin + (size_t)s0 * 64 + lane * 8);
        half8 v1 = *(const half8*)(Tin + (size_t)s1 * 64 + lane * 8);
        half8 v2 = *(const half8*)(Tin + (size_t)s2 * 64 + lane * 8);
        half8 v3 = *(const half8*)(Tin + (size_t)s3 * 64 + lane * 8);
        half8 v4 = *(const half8*)(Tin + (size_t)s4 * 64 + lane * 8);
        half8 v5 = *(const half8*)(Tin + (size_t)s5 * 64 + lane * 8);
        half8 v6 = *(const half8*)(Tin + (size_t)s6 * 64 + lane * 8);
        half8 v7 = *(const half8*)(Tin + (size_t)s7 * 64 + lane * 8);
        #pragma unroll
        for (int j = 0; j < 8; ++j)
            acc[j] += (((float)v0[j] + (float)v1[j]) + ((float)v2[j] + (float)v3[j]))
                    + (((float)v4[j] + (float)v5[j]) + ((float)v6[j] + (float)v7[j]));
    }
    for (; e + 3 < end; e += 4) {
        int s0 = csr[e], s1 = csr[e + 1], s2 = csr[e + 2], s3 = csr[e + 3];
        half8 v0 = *(const half8*)(Tin + (size_t)s0 * 64 + lane * 8);
        half8 v1 = *(const half8*)(Tin + (size_t)s1 * 64 + lane * 8);
        half8 v2 = *(const half8*)(Tin + (size_t)s2 * 64 + lane * 8);
        half8 v3 = *(const half8*)(Tin + (size_t)s3 * 64 + lane * 8);
        #pragma unroll
        for (int j = 0; j < 8; ++j)
            acc[j] += ((float)v0[j] + (float)v1[j]) + ((float)v2[j] + (float)v3[j]);
    }
    for (; e < end; ++e) {
        half8 v = *(const half8*)(Tin + (size_t)csr[e] * 64 + lane * 8);
        #pragma unroll
        for (int j = 0; j < 8; ++j) acc[j] += (float)v[j];
    }
    float sc = dinv[node];
    half8 y = *(const half8*)(Yadd + (size_t)node * 256 + lane * 8);
    if (OUT_F32) {
        float* o = (float*)Tout + (size_t)node * 64 + lane * 8;
        float4 o0, o1;
        o0.x = acc[0] * sc + (float)y[0] + cvec[lane * 8 + 0];
        o0.y = acc[1] * sc + (float)y[1] + cvec[lane * 8 + 1];
        o0.z = acc[2] * sc + (float)y[2] + cvec[lane * 8 + 2];
        o0.w = acc[3] * sc + (float)y[3] + cvec[lane * 8 + 3];
        o1.x = acc[4] * sc + (float)y[4] + cvec[lane * 8 + 4];
        o1.y = acc[5] * sc + (float)y[5] + cvec[lane * 8 + 5];
        o1.z = acc[6] * sc + (float)y[6] + cvec[lane * 8 + 6];
        o1.w = acc[7] * sc + (float)y[7] + cvec[lane * 8 + 7];
        *(float4*)o = o0;
        *(float4*)(o + 4) = o1;
    } else {
        half8 o;
        #pragma unroll
        for (int j = 0; j < 8; ++j)
            o[j] = (_Float16)(acc[j] * sc + (float)y[j] + cvec[lane * 8 + j]);
        *(half8*)((_Float16*)Tout + (size_t)node * 64 + lane * 8) = o;
    }
}

extern "C" void kernel_launch(void* const* d_in, const int* in_sizes, int n_in,
                              void* d_out, int out_size, void* d_ws, size_t ws_size,
                              hipStream_t stream) {
    const float* x    = (const float*)d_in[0];
    const int*   esrc = (const int*)d_in[1];
    const int*   edst = (const int*)d_in[2];
    const float* W0s  = (const float*)d_in[3];
    const float* W0n  = (const float*)d_in[4];
    const float* b0   = (const float*)d_in[5];
    const float* W1s  = (const float*)d_in[6];
    const float* W1n  = (const float*)d_in[7];
    const float* b1   = (const float*)d_in[8];
    const float* W2s  = (const float*)d_in[9];
    const float* W2n  = (const float*)d_in[10];
    const float* b2   = (const float*)d_in[11];
    const float* Wfc  = (const float*)d_in[12];
    const float* bfc  = (const float*)d_in[13];
    float* out = (float*)d_out;

    // ---- workspace layout ----
    _Float16* Y   = (_Float16*)d_ws;                  // N x 256  [Y0|Y1|Y2|Y3]
    _Float16* Ta  = Y + (size_t)NN * 256;             // N x 64
    _Float16* Tb  = Ta + (size_t)NN * 64;             // N x 64
    _Float16* Tc  = Tb + (size_t)NN * 64;             // N x 64 (dense Y3 copy)
    _Float16* BT  = Tc + (size_t)NN * 64;             // 256 x 128
    float* C2     = (float*)(BT + 256 * 128);         // 515 x 256
    float* C3     = C2 + CROWS * 256;                 // 515 x 256
    float* Vf     = C3 + CROWS * 256;                 // 515 x 64
    float* dinv   = Vf + CROWS * 64;                  // N
    int* cnt      = (int*)(dinv + NN);                // N   (memset target)
    int* offs     = cnt + NN;                         // N+1
    int* blockSums = offs + NN + 1;                   // SCAN_BLOCKS
    unsigned short* rank = (unsigned short*)(blockSums + SCAN_BLOCKS);  // E
    unsigned short* csr  = rank + NE;                 // E

    // D1: zero the histogram counters
    hipMemsetAsync(cnt, 0, (size_t)NN * sizeof(int), stream);

    // D2: weight-compose layer0->1 || degree histogram first half
    k_composeF_hist<<<CF_BLOCKS + HBH, 256, 0, stream>>>(
        edst, cnt, rank, W0s, W0n, b0, W1s, W1n, b1, C2);

    // D3: weight-compose layer2 || degree histogram second half
    k_composeM_hist2<<<CF_BLOCKS + HBH, 256, 0, stream>>>(
        edst, cnt, rank, C2, W2s, W2n, b2, C3);

    // D4: final compose (Vf + BT) || per-block degree sums
    k_composeL_scanA<<<CL_BLOCKS + SCAN_BLOCKS, 256, 0, stream>>>(
        cnt, blockSums, C3, Wfc, bfc, Vf, BT);

    // D5: gemm Y cols 0..127 || final scan w/ inline top scan (offs, dinv)
    k_gemmA_scanF<<<GA_BLOCKS + SCAN_BLOCKS, 256, 0, stream>>>(
        cnt, blockSums, offs, dinv, x, BT, Y, Tc);

    // D6: gemm Y cols 128..255 (+Tc) || CSR placement, 4 edges/thread
    k_gemmB_place<<<GA_BLOCKS + HB2, 256, 0, stream>>>(
        esrc, edst, rank, offs, csr, x, BT, Y, Tc);

    // D7-9: output-side propagation: out = Y0 + c1 + A(Y1 + c2 + A(Y2 + c3 + A*Y3))
    // Plain dispatches: kernel-boundary sync is far cheaper than grid.sync's
    // device-scope fencing on non-coherent per-XCD L2s (round-1 lesson: 859 µs coop).
    const int ggrid = (NN + 31) / 32;
    gather64<false><<<ggrid, 256, 0, stream>>>(
        Tc, csr, offs, dinv, Y + 128, Vf + (size_t)514 * 64, (void*)Ta, NN);
    gather64<false><<<ggrid, 256, 0, stream>>>(
        Ta, csr, offs, dinv, Y + 64, Vf + (size_t)513 * 64, (void*)Tb, NN);
    gather64<true><<<ggrid, 256, 0, stream>>>(
        Tb, csr, offs, dinv, Y, Vf + (size_t)512 * 64, (void*)out, NN);
}